// Round 1
// baseline (601.545 us; speedup 1.0000x reference)
//
#include <hip/hip_runtime.h>

// Problem constants (taken dynamically from in_sizes where possible)
static constexpr int EDIM = 128;   // embedding size
static constexpr int FIN  = 256;   // input features

// ---------------------------------------------------------------------------
// Scalars: A = a_low + a_mid, B = b_low - c_mid  (gamma reductions, K=2)
// alpha = [-1e-9, 1+1e-9]
// ---------------------------------------------------------------------------
__global__ void k_scalars(const float* __restrict__ lg,
                          const float* __restrict__ mg,
                          float* __restrict__ sc) {
    if (threadIdx.x == 0 && blockIdx.x == 0) {
        const float a0 = -1e-9f, a1 = 1.0f + 1e-9f;
        float a_low = 0.f, b_low = 0.f, a_mid = 0.f, c_mid = 0.f;
        for (int i = 0; i < 5; ++i) {
            float l0 = fmaxf(lg[2*i], 0.f), l1 = fmaxf(lg[2*i+1], 0.f);
            a_low += l0 * a0 + l1 * a1;
            b_low += l0 * (1.f - a0) + l1 * (1.f - a1);
            float m0 = fmaxf(mg[2*i], 0.f), m1 = fmaxf(mg[2*i+1], 0.f);
            a_mid += m0 + m1;
            c_mid += m0 * a0 + m1 * a1;
        }
        sc[0] = a_low + a_mid;   // coefficient on adj_support
        sc[1] = b_low - c_mid;   // coefficient on support
    }
}

// ---------------------------------------------------------------------------
// GEMM1: S[M,128] = relu(F[M,256] @ W[256,128])   (fp32 vector)
// BM=64, BK=32, 256 threads, per-thread 8 rows x 4 cols
// ---------------------------------------------------------------------------
__global__ __launch_bounds__(256) void k_gemm1(const float* __restrict__ F,
                                               const float* __restrict__ W,
                                               float* __restrict__ S, int M) {
    __shared__ float Af[64][33];     // +1 pad
    __shared__ float Bf[32][128];
    const int tid = threadIdx.x;
    const int bm  = blockIdx.x * 64;
    const int tr  = tid >> 5;        // 0..7  -> rows tr*8..tr*8+7
    const int tc  = tid & 31;        // 0..31 -> cols tc*4..tc*4+3

    float acc[8][4] = {};

    for (int kt = 0; kt < FIN; kt += 32) {
        // A tile 64x32: 512 float4, 2 per thread
        #pragma unroll
        for (int i = 0; i < 2; ++i) {
            int idx = tid + i * 256;            // 0..511
            int r = idx >> 3;
            int c = (idx & 7) << 2;
            int gr = bm + r;
            float4 v = make_float4(0.f, 0.f, 0.f, 0.f);
            if (gr < M) v = *(const float4*)(F + (size_t)gr * FIN + kt + c);
            Af[r][c + 0] = v.x; Af[r][c + 1] = v.y;
            Af[r][c + 2] = v.z; Af[r][c + 3] = v.w;
        }
        // B tile 32x128: 1024 float4, 4 per thread
        #pragma unroll
        for (int i = 0; i < 4; ++i) {
            int idx = tid + i * 256;            // 0..1023
            int r = idx >> 5;
            int c = (idx & 31) << 2;
            *(float4*)(&Bf[r][c]) = *(const float4*)(W + (size_t)(kt + r) * EDIM + c);
        }
        __syncthreads();

        #pragma unroll
        for (int k = 0; k < 32; ++k) {
            float a[8];
            #pragma unroll
            for (int i = 0; i < 8; ++i) a[i] = Af[tr * 8 + i][k];
            float4 bv = *(float4*)(&Bf[k][tc * 4]);
            float b[4] = {bv.x, bv.y, bv.z, bv.w};
            #pragma unroll
            for (int i = 0; i < 8; ++i)
                #pragma unroll
                for (int j = 0; j < 4; ++j)
                    acc[i][j] = fmaf(a[i], b[j], acc[i][j]);
        }
        __syncthreads();
    }

    #pragma unroll
    for (int i = 0; i < 8; ++i) {
        int gr = bm + tr * 8 + i;
        if (gr < M) {
            float4 v;
            v.x = fmaxf(acc[i][0], 0.f);
            v.y = fmaxf(acc[i][1], 0.f);
            v.z = fmaxf(acc[i][2], 0.f);
            v.w = fmaxf(acc[i][3], 0.f);
            *(float4*)(S + (size_t)gr * EDIM + tc * 4) = v;
        }
    }
}

// ---------------------------------------------------------------------------
// Scatter: adj[row] += w_e * sup[col] over edges. One wave (64 lanes) / edge,
// 2 floats per lane.
// ---------------------------------------------------------------------------
__global__ __launch_bounds__(256) void k_scatter(const int* __restrict__ ei,
                                                 const float* __restrict__ ew,
                                                 const float* __restrict__ sup,
                                                 float* __restrict__ adj,
                                                 int ne) {
    int wave = (blockIdx.x * blockDim.x + threadIdx.x) >> 6;
    int lane = threadIdx.x & 63;
    if (wave >= ne) return;
    int row = ei[wave];
    int col = ei[ne + wave];
    float w = ew[wave];
    float2 v = *(const float2*)(sup + (size_t)col * EDIM + lane * 2);
    atomicAdd(adj + (size_t)row * EDIM + lane * 2 + 0, w * v.x);
    atomicAdd(adj + (size_t)row * EDIM + lane * 2 + 1, w * v.y);
}

// ---------------------------------------------------------------------------
// GEMM2: out[M,128] = (Aa*adj + Bb*sup) @ vw^T + 2*vb   (K = 128)
// ---------------------------------------------------------------------------
__global__ __launch_bounds__(256) void k_gemm2(const float* __restrict__ adj,
                                               const float* __restrict__ sup,
                                               const float* __restrict__ vw,
                                               const float* __restrict__ vb,
                                               const float* __restrict__ sc,
                                               float* __restrict__ out, int M) {
    __shared__ float Af[64][33];
    __shared__ float Bf[32][132];    // transposed vw tile, padded for 16B-aligned rows
    const int tid = threadIdx.x;
    const int bm  = blockIdx.x * 64;
    const int tr  = tid >> 5;
    const int tc  = tid & 31;
    const float Aa = sc[0];
    const float Bb = sc[1];

    float acc[8][4] = {};

    for (int kt = 0; kt < EDIM; kt += 32) {
        // A tile: combine Aa*adj + Bb*sup on the fly
        #pragma unroll
        for (int i = 0; i < 2; ++i) {
            int idx = tid + i * 256;
            int r = idx >> 3;
            int c = (idx & 7) << 2;
            int gr = bm + r;
            float4 v = make_float4(0.f, 0.f, 0.f, 0.f);
            if (gr < M) {
                float4 va = *(const float4*)(adj + (size_t)gr * EDIM + kt + c);
                float4 vs = *(const float4*)(sup + (size_t)gr * EDIM + kt + c);
                v.x = Aa * va.x + Bb * vs.x;
                v.y = Aa * va.y + Bb * vs.y;
                v.z = Aa * va.z + Bb * vs.z;
                v.w = Aa * va.w + Bb * vs.w;
            }
            Af[r][c + 0] = v.x; Af[r][c + 1] = v.y;
            Af[r][c + 2] = v.z; Af[r][c + 3] = v.w;
        }
        // B tile: Bf[k][col] = vw[col][kt+k]  (transpose load)
        #pragma unroll
        for (int i = 0; i < 4; ++i) {
            int idx = tid + i * 256;            // 0..1023
            int col = idx >> 3;                 // 0..127
            int k0  = (idx & 7) << 2;           // 0,4,...,28
            float4 v = *(const float4*)(vw + (size_t)col * EDIM + kt + k0);
            Bf[k0 + 0][col] = v.x;
            Bf[k0 + 1][col] = v.y;
            Bf[k0 + 2][col] = v.z;
            Bf[k0 + 3][col] = v.w;
        }
        __syncthreads();

        #pragma unroll
        for (int k = 0; k < 32; ++k) {
            float a[8];
            #pragma unroll
            for (int i = 0; i < 8; ++i) a[i] = Af[tr * 8 + i][k];
            float4 bv = *(float4*)(&Bf[k][tc * 4]);
            float b[4] = {bv.x, bv.y, bv.z, bv.w};
            #pragma unroll
            for (int i = 0; i < 8; ++i)
                #pragma unroll
                for (int j = 0; j < 4; ++j)
                    acc[i][j] = fmaf(a[i], b[j], acc[i][j]);
        }
        __syncthreads();
    }

    float4 bvb = *(const float4*)(vb + tc * 4);
    #pragma unroll
    for (int i = 0; i < 8; ++i) {
        int gr = bm + tr * 8 + i;
        if (gr < M) {
            float4 v;
            v.x = acc[i][0] + 2.f * bvb.x;
            v.y = acc[i][1] + 2.f * bvb.y;
            v.z = acc[i][2] + 2.f * bvb.z;
            v.w = acc[i][3] + 2.f * bvb.w;
            *(float4*)(out + (size_t)gr * EDIM + tc * 4) = v;
        }
    }
}

// ---------------------------------------------------------------------------
extern "C" void kernel_launch(void* const* d_in, const int* in_sizes, int n_in,
                              void* d_out, int out_size, void* d_ws, size_t ws_size,
                              hipStream_t stream) {
    const float* feature = (const float*)d_in[0];
    const int*   eidx    = (const int*)d_in[1];   // [2, NE] int32
    const float* ew      = (const float*)d_in[2];
    const float* weight  = (const float*)d_in[3];
    const float* lg      = (const float*)d_in[4];
    const float* mg      = (const float*)d_in[5];
    // d_in[6..9] = q_w,q_b,k_w,k_b are provably unused (softmax over query axis
    // followed by sum over query axis makes attention weights sum to 1)
    const float* vw      = (const float*)d_in[10];
    const float* vb      = (const float*)d_in[11];
    float* out = (float*)d_out;

    const int M  = in_sizes[0] / FIN;   // 50000
    const int NE = in_sizes[2];         // 600000

    const size_t matBytes = (size_t)M * EDIM * sizeof(float);
    char* ws = (char*)d_ws;
    float* sup = (float*)ws;                        // [M,128]
    float* adj = (float*)(ws + matBytes);           // [M,128]
    float* sc  = (float*)(ws + 2 * matBytes);       // 2 scalars

    k_scalars<<<1, 64, 0, stream>>>(lg, mg, sc);
    hipMemsetAsync(adj, 0, matBytes, stream);

    int gRows = (M + 63) / 64;
    k_gemm1<<<gRows, 256, 0, stream>>>(feature, weight, sup, M);

    int gScatter = (NE + 3) / 4;                    // 4 waves (edges) per block
    k_scatter<<<gScatter, 256, 0, stream>>>(eidx, ew, sup, adj, NE);

    k_gemm2<<<gRows, 256, 0, stream>>>(adj, sup, vw, vb, sc, out, M);
}

// Round 2
// 261.513 us; speedup vs baseline: 2.3002x; 2.3002x over previous
//
#include <hip/hip_runtime.h>
#include <hip/hip_bf16.h>

static constexpr int EDIM = 128;   // embedding size
static constexpr int FIN  = 256;   // input features

struct bf16x4 { __hip_bfloat162 lo, hi; };

// ---------------------------------------------------------------------------
// Scalars: A = a_low + a_mid (coeff on adj_support), B = b_low - c_mid (on support)
// alpha = [-1e-9, 1+1e-9]
// ---------------------------------------------------------------------------
__global__ void k_scalars(const float* __restrict__ lg,
                          const float* __restrict__ mg,
                          float* __restrict__ sc) {
    if (threadIdx.x == 0 && blockIdx.x == 0) {
        const float a0 = -1e-9f, a1 = 1.0f + 1e-9f;
        float a_low = 0.f, b_low = 0.f, a_mid = 0.f, c_mid = 0.f;
        for (int i = 0; i < 5; ++i) {
            float l0 = fmaxf(lg[2*i], 0.f), l1 = fmaxf(lg[2*i+1], 0.f);
            a_low += l0 * a0 + l1 * a1;
            b_low += l0 * (1.f - a0) + l1 * (1.f - a1);
            float m0 = fmaxf(mg[2*i], 0.f), m1 = fmaxf(mg[2*i+1], 0.f);
            a_mid += m0 + m1;
            c_mid += m0 * a0 + m1 * a1;
        }
        sc[0] = a_low + a_mid;
        sc[1] = b_low - c_mid;
    }
}

// ---------------------------------------------------------------------------
// GEMM1: sup[M,128] (bf16) = relu(F[M,256] @ W[256,128])   (fp32 vector math)
// ---------------------------------------------------------------------------
__global__ __launch_bounds__(256) void k_gemm1(const float* __restrict__ F,
                                               const float* __restrict__ W,
                                               __hip_bfloat162* __restrict__ supb,
                                               int M) {
    __shared__ float Af[64][33];
    __shared__ float Bf[32][128];
    const int tid = threadIdx.x;
    const int bm  = blockIdx.x * 64;
    const int tr  = tid >> 5;
    const int tc  = tid & 31;

    float acc[8][4] = {};

    for (int kt = 0; kt < FIN; kt += 32) {
        #pragma unroll
        for (int i = 0; i < 2; ++i) {
            int idx = tid + i * 256;
            int r = idx >> 3;
            int c = (idx & 7) << 2;
            int gr = bm + r;
            float4 v = make_float4(0.f, 0.f, 0.f, 0.f);
            if (gr < M) v = *(const float4*)(F + (size_t)gr * FIN + kt + c);
            Af[r][c + 0] = v.x; Af[r][c + 1] = v.y;
            Af[r][c + 2] = v.z; Af[r][c + 3] = v.w;
        }
        #pragma unroll
        for (int i = 0; i < 4; ++i) {
            int idx = tid + i * 256;
            int r = idx >> 5;
            int c = (idx & 31) << 2;
            *(float4*)(&Bf[r][c]) = *(const float4*)(W + (size_t)(kt + r) * EDIM + c);
        }
        __syncthreads();

        #pragma unroll
        for (int k = 0; k < 32; ++k) {
            float a[8];
            #pragma unroll
            for (int i = 0; i < 8; ++i) a[i] = Af[tr * 8 + i][k];
            float4 bv = *(float4*)(&Bf[k][tc * 4]);
            float b[4] = {bv.x, bv.y, bv.z, bv.w};
            #pragma unroll
            for (int i = 0; i < 8; ++i)
                #pragma unroll
                for (int j = 0; j < 4; ++j)
                    acc[i][j] = fmaf(a[i], b[j], acc[i][j]);
        }
        __syncthreads();
    }

    #pragma unroll
    for (int i = 0; i < 8; ++i) {
        int gr = bm + tr * 8 + i;
        if (gr < M) {
            bf16x4 o;
            o.lo = __float22bfloat162_rn(make_float2(fmaxf(acc[i][0], 0.f),
                                                     fmaxf(acc[i][1], 0.f)));
            o.hi = __float22bfloat162_rn(make_float2(fmaxf(acc[i][2], 0.f),
                                                     fmaxf(acc[i][3], 0.f)));
            *(bf16x4*)(supb + (size_t)gr * 64 + tc * 2) = o;
        }
    }
}

// ---------------------------------------------------------------------------
// CSR build: count -> exclusive scan (3 kernels) -> fill edge order
// ---------------------------------------------------------------------------
__global__ void k_count(const int* __restrict__ ei, int* __restrict__ start, int ne) {
    int e = blockIdx.x * blockDim.x + threadIdx.x;
    if (e < ne) atomicAdd(&start[ei[e]], 1);
}

__global__ void k_scan1(const int* __restrict__ cnt, int* __restrict__ bsum, int n) {
    __shared__ int sh[256];
    int t = threadIdx.x;
    int i = blockIdx.x * 256 + t;
    sh[t] = (i < n) ? cnt[i] : 0;
    __syncthreads();
    for (int s = 128; s > 0; s >>= 1) {
        if (t < s) sh[t] += sh[t + s];
        __syncthreads();
    }
    if (t == 0) bsum[blockIdx.x] = sh[0];
}

__global__ void k_scan2(int* __restrict__ bsum, int nb) {
    __shared__ int sh[256];
    int t = threadIdx.x;
    int v = (t < nb) ? bsum[t] : 0;
    sh[t] = v;
    __syncthreads();
    for (int off = 1; off < 256; off <<= 1) {
        int x = (t >= off) ? sh[t - off] : 0;
        __syncthreads();
        sh[t] += x;
        __syncthreads();
    }
    if (t < nb) bsum[t] = sh[t] - v;   // exclusive
}

__global__ void k_scan3(int* __restrict__ start, const int* __restrict__ bsum, int n) {
    __shared__ int sh[256];
    int t = threadIdx.x;
    int i = blockIdx.x * 256 + t;
    int v = (i < n) ? start[i] : 0;
    sh[t] = v;
    __syncthreads();
    for (int off = 1; off < 256; off <<= 1) {
        int x = (t >= off) ? sh[t - off] : 0;
        __syncthreads();
        sh[t] += x;
        __syncthreads();
    }
    if (i < n) start[i] = sh[t] - v + bsum[blockIdx.x];   // exclusive start
}

__global__ void k_fill(const int* __restrict__ ei, int* __restrict__ start,
                       int* __restrict__ eord, int ne) {
    int e = blockIdx.x * blockDim.x + threadIdx.x;
    if (e >= ne) return;
    int pos = atomicAdd(&start[ei[e]], 1);   // start[r] ends as end-of-row r
    eord[pos] = e;
}

// ---------------------------------------------------------------------------
// Gather: one wave per row. adj[row] = sum_e w_e * sup[col_e]  (fp32 out)
// ---------------------------------------------------------------------------
__global__ __launch_bounds__(256) void k_gather(const int* __restrict__ ei,
                                                const float* __restrict__ ew,
                                                const int* __restrict__ eord,
                                                const int* __restrict__ start,
                                                const __hip_bfloat162* __restrict__ supb,
                                                float* __restrict__ adj,
                                                int n, int ne) {
    int wave = (blockIdx.x * blockDim.x + threadIdx.x) >> 6;
    int lane = threadIdx.x & 63;
    if (wave >= n) return;
    int begin = (wave == 0) ? 0 : start[wave - 1];
    int end   = start[wave];
    float2 acc = make_float2(0.f, 0.f);
    for (int j = begin; j < end; ++j) {
        int e   = eord[j];
        int col = ei[ne + e];
        float w = ew[e];
        float2 v = __bfloat1622float2(supb[(size_t)col * 64 + lane]);
        acc.x = fmaf(w, v.x, acc.x);
        acc.y = fmaf(w, v.y, acc.y);
    }
    *(float2*)(adj + (size_t)wave * EDIM + lane * 2) = acc;
}

// ---------------------------------------------------------------------------
// GEMM2: out[M,128] = (Aa*adj + Bb*sup) @ vw^T + 2*vb   (K = 128)
// ---------------------------------------------------------------------------
__global__ __launch_bounds__(256) void k_gemm2(const float* __restrict__ adj,
                                               const __hip_bfloat162* __restrict__ supb,
                                               const float* __restrict__ vw,
                                               const float* __restrict__ vb,
                                               const float* __restrict__ sc,
                                               float* __restrict__ out, int M) {
    __shared__ float Af[64][33];
    __shared__ float Bf[32][132];
    const int tid = threadIdx.x;
    const int bm  = blockIdx.x * 64;
    const int tr  = tid >> 5;
    const int tc  = tid & 31;
    const float Aa = sc[0];
    const float Bb = sc[1];

    float acc[8][4] = {};

    for (int kt = 0; kt < EDIM; kt += 32) {
        #pragma unroll
        for (int i = 0; i < 2; ++i) {
            int idx = tid + i * 256;
            int r = idx >> 3;
            int c = (idx & 7) << 2;
            int gr = bm + r;
            float4 v = make_float4(0.f, 0.f, 0.f, 0.f);
            if (gr < M) {
                float4 va = *(const float4*)(adj + (size_t)gr * EDIM + kt + c);
                bf16x4 vs = *(const bf16x4*)(supb + (size_t)gr * 64 + ((kt + c) >> 1));
                float2 f0 = __bfloat1622float2(vs.lo);
                float2 f1 = __bfloat1622float2(vs.hi);
                v.x = Aa * va.x + Bb * f0.x;
                v.y = Aa * va.y + Bb * f0.y;
                v.z = Aa * va.z + Bb * f1.x;
                v.w = Aa * va.w + Bb * f1.y;
            }
            Af[r][c + 0] = v.x; Af[r][c + 1] = v.y;
            Af[r][c + 2] = v.z; Af[r][c + 3] = v.w;
        }
        // B tile: Bf[k][col] = vw[col][kt+k]  (transpose load)
        #pragma unroll
        for (int i = 0; i < 4; ++i) {
            int idx = tid + i * 256;
            int col = idx >> 3;
            int k0  = (idx & 7) << 2;
            float4 v = *(const float4*)(vw + (size_t)col * EDIM + kt + k0);
            Bf[k0 + 0][col] = v.x;
            Bf[k0 + 1][col] = v.y;
            Bf[k0 + 2][col] = v.z;
            Bf[k0 + 3][col] = v.w;
        }
        __syncthreads();

        #pragma unroll
        for (int k = 0; k < 32; ++k) {
            float a[8];
            #pragma unroll
            for (int i = 0; i < 8; ++i) a[i] = Af[tr * 8 + i][k];
            float4 bv = *(float4*)(&Bf[k][tc * 4]);
            float b[4] = {bv.x, bv.y, bv.z, bv.w};
            #pragma unroll
            for (int i = 0; i < 8; ++i)
                #pragma unroll
                for (int j = 0; j < 4; ++j)
                    acc[i][j] = fmaf(a[i], b[j], acc[i][j]);
        }
        __syncthreads();
    }

    float4 bvb = *(const float4*)(vb + tc * 4);
    #pragma unroll
    for (int i = 0; i < 8; ++i) {
        int gr = bm + tr * 8 + i;
        if (gr < M) {
            float4 v;
            v.x = acc[i][0] + 2.f * bvb.x;
            v.y = acc[i][1] + 2.f * bvb.y;
            v.z = acc[i][2] + 2.f * bvb.z;
            v.w = acc[i][3] + 2.f * bvb.w;
            *(float4*)(out + (size_t)gr * EDIM + tc * 4) = v;
        }
    }
}

// ---------------------------------------------------------------------------
extern "C" void kernel_launch(void* const* d_in, const int* in_sizes, int n_in,
                              void* d_out, int out_size, void* d_ws, size_t ws_size,
                              hipStream_t stream) {
    const float* feature = (const float*)d_in[0];
    const int*   eidx    = (const int*)d_in[1];   // [2, NE] int32
    const float* ew      = (const float*)d_in[2];
    const float* weight  = (const float*)d_in[3];
    const float* lg      = (const float*)d_in[4];
    const float* mg      = (const float*)d_in[5];
    // d_in[6..9] = q_w,q_b,k_w,k_b provably unused: softmax over the query axis
    // followed by sum over the query axis makes each k-column of w sum to 1.
    const float* vw      = (const float*)d_in[10];
    const float* vb      = (const float*)d_in[11];
    float* out = (float*)d_out;

    const int M  = in_sizes[0] / FIN;   // 50000
    const int NE = in_sizes[2];         // 600000

    // workspace layout (~41 MB, fits the >=51.2 MB proven in round 1)
    char* ws = (char*)d_ws;
    float* adj            = (float*)ws;                              // 25.6 MB
    __hip_bfloat162* supb = (__hip_bfloat162*)(ws + (size_t)M * EDIM * 4);  // 12.8 MB
    char*  p = ws + (size_t)M * EDIM * 4 + (size_t)M * EDIM * 2;
    int*   start = (int*)p;          p += (size_t)M * 4;             // 200 KB
    int*   bsum  = (int*)p;          p += 256 * 4;
    int*   eord  = (int*)p;          p += (size_t)NE * 4;            // 2.4 MB
    float* sc    = (float*)p;

    const int nb = (M + 255) / 256;           // 196 scan blocks (<=256)

    k_scalars<<<1, 64, 0, stream>>>(lg, mg, sc);
    hipMemsetAsync(start, 0, (size_t)M * 4, stream);

    int gRows = (M + 63) / 64;
    k_gemm1<<<gRows, 256, 0, stream>>>(feature, weight, supb, M);

    int gE = (NE + 255) / 256;
    k_count<<<gE, 256, 0, stream>>>(eidx, start, NE);
    k_scan1<<<nb, 256, 0, stream>>>(start, bsum, M);
    k_scan2<<<1, 256, 0, stream>>>(bsum, nb);
    k_scan3<<<nb, 256, 0, stream>>>(start, bsum, M);
    k_fill<<<gE, 256, 0, stream>>>(eidx, start, eord, NE);

    int gGather = ((M * 64) + 255) / 256;     // one wave per row
    k_gather<<<gGather, 256, 0, stream>>>(eidx, ew, eord, start, supb, adj, M, NE);

    k_gemm2<<<gRows, 256, 0, stream>>>(adj, supb, vw, vb, sc, out, M);
}

// Round 3
// 214.720 us; speedup vs baseline: 2.8015x; 1.2179x over previous
//
#include <hip/hip_runtime.h>
#include <hip/hip_bf16.h>

static constexpr int EDIM = 128;   // embedding size
static constexpr int FIN  = 256;   // input features

struct bf16x4 { __hip_bfloat162 lo, hi; };

// ---------------------------------------------------------------------------
// Scalars: Aa = a_low + a_mid (coeff on adj_support), Bb = b_low - c_mid (on support)
// alpha = [-1e-9, 1+1e-9]
// ---------------------------------------------------------------------------
__global__ void k_scalars(const float* __restrict__ lg,
                          const float* __restrict__ mg,
                          float* __restrict__ sc) {
    if (threadIdx.x == 0 && blockIdx.x == 0) {
        const float a0 = -1e-9f, a1 = 1.0f + 1e-9f;
        float a_low = 0.f, b_low = 0.f, a_mid = 0.f, c_mid = 0.f;
        for (int i = 0; i < 5; ++i) {
            float l0 = fmaxf(lg[2*i], 0.f), l1 = fmaxf(lg[2*i+1], 0.f);
            a_low += l0 * a0 + l1 * a1;
            b_low += l0 * (1.f - a0) + l1 * (1.f - a1);
            float m0 = fmaxf(mg[2*i], 0.f), m1 = fmaxf(mg[2*i+1], 0.f);
            a_mid += m0 + m1;
            c_mid += m0 * a0 + m1 * a1;
        }
        sc[0] = a_low + a_mid;
        sc[1] = b_low - c_mid;
    }
}

// ---------------------------------------------------------------------------
// GEMM1: sup[M,128] (bf16) = relu(F[M,256] @ W[256,128])   (fp32 vector math)
// ---------------------------------------------------------------------------
__global__ __launch_bounds__(256) void k_gemm1(const float* __restrict__ F,
                                               const float* __restrict__ W,
                                               __hip_bfloat162* __restrict__ supb,
                                               int M) {
    __shared__ float Af[64][33];
    __shared__ float Bf[32][128];
    const int tid = threadIdx.x;
    const int bm  = blockIdx.x * 64;
    const int tr  = tid >> 5;
    const int tc  = tid & 31;

    float acc[8][4] = {};

    for (int kt = 0; kt < FIN; kt += 32) {
        #pragma unroll
        for (int i = 0; i < 2; ++i) {
            int idx = tid + i * 256;
            int r = idx >> 3;
            int c = (idx & 7) << 2;
            int gr = bm + r;
            float4 v = make_float4(0.f, 0.f, 0.f, 0.f);
            if (gr < M) v = *(const float4*)(F + (size_t)gr * FIN + kt + c);
            Af[r][c + 0] = v.x; Af[r][c + 1] = v.y;
            Af[r][c + 2] = v.z; Af[r][c + 3] = v.w;
        }
        #pragma unroll
        for (int i = 0; i < 4; ++i) {
            int idx = tid + i * 256;
            int r = idx >> 5;
            int c = (idx & 31) << 2;
            *(float4*)(&Bf[r][c]) = *(const float4*)(W + (size_t)(kt + r) * EDIM + c);
        }
        __syncthreads();

        #pragma unroll
        for (int k = 0; k < 32; ++k) {
            float a[8];
            #pragma unroll
            for (int i = 0; i < 8; ++i) a[i] = Af[tr * 8 + i][k];
            float4 bv = *(float4*)(&Bf[k][tc * 4]);
            float b[4] = {bv.x, bv.y, bv.z, bv.w};
            #pragma unroll
            for (int i = 0; i < 8; ++i)
                #pragma unroll
                for (int j = 0; j < 4; ++j)
                    acc[i][j] = fmaf(a[i], b[j], acc[i][j]);
        }
        __syncthreads();
    }

    #pragma unroll
    for (int i = 0; i < 8; ++i) {
        int gr = bm + tr * 8 + i;
        if (gr < M) {
            bf16x4 o;
            o.lo = __float22bfloat162_rn(make_float2(fmaxf(acc[i][0], 0.f),
                                                     fmaxf(acc[i][1], 0.f)));
            o.hi = __float22bfloat162_rn(make_float2(fmaxf(acc[i][2], 0.f),
                                                     fmaxf(acc[i][3], 0.f)));
            *(bf16x4*)(supb + (size_t)gr * 64 + tc * 2) = o;
        }
    }
}

// ---------------------------------------------------------------------------
// GEMM V: Y[M,128] (bf16) = sup[M,128] @ vw^T      (fp32 vector math)
// ---------------------------------------------------------------------------
__global__ __launch_bounds__(256) void k_gemmV(const __hip_bfloat162* __restrict__ supb,
                                               const float* __restrict__ vw,
                                               __hip_bfloat162* __restrict__ Yb,
                                               int M) {
    __shared__ float Af[64][33];
    __shared__ float Bf[32][132];
    const int tid = threadIdx.x;
    const int bm  = blockIdx.x * 64;
    const int tr  = tid >> 5;
    const int tc  = tid & 31;

    float acc[8][4] = {};

    for (int kt = 0; kt < EDIM; kt += 32) {
        // A tile 64x32 from bf16 sup
        #pragma unroll
        for (int i = 0; i < 2; ++i) {
            int idx = tid + i * 256;
            int r = idx >> 3;
            int c = (idx & 7) << 2;
            int gr = bm + r;
            float4 v = make_float4(0.f, 0.f, 0.f, 0.f);
            if (gr < M) {
                bf16x4 vs = *(const bf16x4*)(supb + (size_t)gr * 64 + ((kt + c) >> 1));
                float2 f0 = __bfloat1622float2(vs.lo);
                float2 f1 = __bfloat1622float2(vs.hi);
                v.x = f0.x; v.y = f0.y; v.z = f1.x; v.w = f1.y;
            }
            Af[r][c + 0] = v.x; Af[r][c + 1] = v.y;
            Af[r][c + 2] = v.z; Af[r][c + 3] = v.w;
        }
        // B tile: Bf[k][col] = vw[col][kt+k]  (transpose load)
        #pragma unroll
        for (int i = 0; i < 4; ++i) {
            int idx = tid + i * 256;
            int col = idx >> 3;
            int k0  = (idx & 7) << 2;
            float4 v = *(const float4*)(vw + (size_t)col * EDIM + kt + k0);
            Bf[k0 + 0][col] = v.x;
            Bf[k0 + 1][col] = v.y;
            Bf[k0 + 2][col] = v.z;
            Bf[k0 + 3][col] = v.w;
        }
        __syncthreads();

        #pragma unroll
        for (int k = 0; k < 32; ++k) {
            float a[8];
            #pragma unroll
            for (int i = 0; i < 8; ++i) a[i] = Af[tr * 8 + i][k];
            float4 bv = *(float4*)(&Bf[k][tc * 4]);
            float b[4] = {bv.x, bv.y, bv.z, bv.w};
            #pragma unroll
            for (int i = 0; i < 8; ++i)
                #pragma unroll
                for (int j = 0; j < 4; ++j)
                    acc[i][j] = fmaf(a[i], b[j], acc[i][j]);
        }
        __syncthreads();
    }

    #pragma unroll
    for (int i = 0; i < 8; ++i) {
        int gr = bm + tr * 8 + i;
        if (gr < M) {
            bf16x4 o;
            o.lo = __float22bfloat162_rn(make_float2(acc[i][0], acc[i][1]));
            o.hi = __float22bfloat162_rn(make_float2(acc[i][2], acc[i][3]));
            *(bf16x4*)(Yb + (size_t)gr * 64 + tc * 2) = o;
        }
    }
}

// ---------------------------------------------------------------------------
// CSR build: count -> exclusive scan (3 kernels) -> fill packed {col, w}
// ---------------------------------------------------------------------------
__global__ void k_count(const int* __restrict__ ei, int* __restrict__ start, int ne) {
    int e = blockIdx.x * blockDim.x + threadIdx.x;
    if (e < ne) atomicAdd(&start[ei[e]], 1);
}

__global__ void k_scan1(const int* __restrict__ cnt, int* __restrict__ bsum, int n) {
    __shared__ int sh[256];
    int t = threadIdx.x;
    int i = blockIdx.x * 256 + t;
    sh[t] = (i < n) ? cnt[i] : 0;
    __syncthreads();
    for (int s = 128; s > 0; s >>= 1) {
        if (t < s) sh[t] += sh[t + s];
        __syncthreads();
    }
    if (t == 0) bsum[blockIdx.x] = sh[0];
}

__global__ void k_scan2(int* __restrict__ bsum, int nb) {
    __shared__ int sh[256];
    int t = threadIdx.x;
    int v = (t < nb) ? bsum[t] : 0;
    sh[t] = v;
    __syncthreads();
    for (int off = 1; off < 256; off <<= 1) {
        int x = (t >= off) ? sh[t - off] : 0;
        __syncthreads();
        sh[t] += x;
        __syncthreads();
    }
    if (t < nb) bsum[t] = sh[t] - v;   // exclusive
}

__global__ void k_scan3(int* __restrict__ start, const int* __restrict__ bsum, int n) {
    __shared__ int sh[256];
    int t = threadIdx.x;
    int i = blockIdx.x * 256 + t;
    int v = (i < n) ? start[i] : 0;
    sh[t] = v;
    __syncthreads();
    for (int off = 1; off < 256; off <<= 1) {
        int x = (t >= off) ? sh[t - off] : 0;
        __syncthreads();
        sh[t] += x;
        __syncthreads();
    }
    if (i < n) start[i] = sh[t] - v + bsum[blockIdx.x];   // exclusive start
}

__global__ void k_fill(const int* __restrict__ ei, const float* __restrict__ ew,
                       int* __restrict__ start, int2* __restrict__ colw, int ne) {
    int e = blockIdx.x * blockDim.x + threadIdx.x;
    if (e >= ne) return;
    int pos = atomicAdd(&start[ei[e]], 1);   // start[r] ends as end-of-row r
    colw[pos] = make_int2(ei[ne + e], __float_as_int(ew[e]));
}

// ---------------------------------------------------------------------------
// Fused gather + epilogue: out[row] = Aa * sum_e w_e * Y[col_e] + Bb*Y[row] + 2*vb
// One wave per row; edge list loaded lane-parallel, broadcast via __shfl.
// ---------------------------------------------------------------------------
__global__ __launch_bounds__(256) void k_gather(const int2* __restrict__ colw,
                                                const int* __restrict__ start,
                                                const __hip_bfloat162* __restrict__ Yb,
                                                const float* __restrict__ vb,
                                                const float* __restrict__ sc,
                                                float* __restrict__ out, int n) {
    int wave = (blockIdx.x * blockDim.x + threadIdx.x) >> 6;
    int lane = threadIdx.x & 63;
    if (wave >= n) return;
    int begin = (wave == 0) ? 0 : start[wave - 1];
    int end   = start[wave];
    const float Aa = sc[0];
    const float Bb = sc[1];

    float2 acc = make_float2(0.f, 0.f);
    for (int base = begin; base < end; base += 64) {
        int m = end - base;
        int2 cw = make_int2(0, 0);
        if (lane < m) cw = colw[base + lane];
        int cnt = (m < 64) ? m : 64;
        for (int j = 0; j < cnt; ++j) {
            int col   = __shfl(cw.x, j);
            float w   = __shfl(__int_as_float(cw.y), j);
            float2 v  = __bfloat1622float2(Yb[(size_t)col * 64 + lane]);
            acc.x = fmaf(w, v.x, acc.x);
            acc.y = fmaf(w, v.y, acc.y);
        }
    }
    float2 y = __bfloat1622float2(Yb[(size_t)wave * 64 + lane]);
    float2 b = *(const float2*)(vb + lane * 2);
    float2 o;
    o.x = fmaf(Aa, acc.x, fmaf(Bb, y.x, 2.f * b.x));
    o.y = fmaf(Aa, acc.y, fmaf(Bb, y.y, 2.f * b.y));
    *(float2*)(out + (size_t)wave * EDIM + lane * 2) = o;
}

// ---------------------------------------------------------------------------
extern "C" void kernel_launch(void* const* d_in, const int* in_sizes, int n_in,
                              void* d_out, int out_size, void* d_ws, size_t ws_size,
                              hipStream_t stream) {
    const float* feature = (const float*)d_in[0];
    const int*   eidx    = (const int*)d_in[1];   // [2, NE] int32
    const float* ew      = (const float*)d_in[2];
    const float* weight  = (const float*)d_in[3];
    const float* lg      = (const float*)d_in[4];
    const float* mg      = (const float*)d_in[5];
    // d_in[6..9] = q_w,q_b,k_w,k_b provably unused: softmax over the query axis
    // followed by sum over the query axis makes each k-column of w sum to 1.
    const float* vw      = (const float*)d_in[10];
    const float* vb      = (const float*)d_in[11];
    float* out = (float*)d_out;

    const int M  = in_sizes[0] / FIN;   // 50000
    const int NE = in_sizes[2];         // 600000

    // workspace layout (~31 MB)
    char* ws = (char*)d_ws;
    __hip_bfloat162* supb = (__hip_bfloat162*)ws;                          // 12.8 MB
    __hip_bfloat162* Yb   = (__hip_bfloat162*)(ws + (size_t)M * EDIM * 2); // 12.8 MB
    char* p = ws + 2 * (size_t)M * EDIM * 2;
    int2* colw  = (int2*)p;          p += (size_t)NE * 8;                  // 4.8 MB
    int*  start = (int*)p;           p += (size_t)M * 4;                   // 200 KB
    int*  bsum  = (int*)p;           p += 256 * 4;
    float* sc   = (float*)p;

    const int nb = (M + 255) / 256;

    k_scalars<<<1, 64, 0, stream>>>(lg, mg, sc);
    hipMemsetAsync(start, 0, (size_t)M * 4, stream);

    int gRows = (M + 63) / 64;
    k_gemm1<<<gRows, 256, 0, stream>>>(feature, weight, supb, M);

    int gE = (NE + 255) / 256;
    k_count<<<gE, 256, 0, stream>>>(eidx, start, NE);
    k_scan1<<<nb, 256, 0, stream>>>(start, bsum, M);
    k_scan2<<<1, 256, 0, stream>>>(bsum, nb);
    k_scan3<<<nb, 256, 0, stream>>>(start, bsum, M);
    k_fill<<<gE, 256, 0, stream>>>(eidx, ew, start, colw, NE);

    k_gemmV<<<gRows, 256, 0, stream>>>(supb, vw, Yb, M);

    int gGather = ((M * 64) + 255) / 256;     // one wave per row
    k_gather<<<gGather, 256, 0, stream>>>(colw, start, Yb, vb, sc, out, M);
}

// Round 4
// 165.469 us; speedup vs baseline: 3.6354x; 1.2976x over previous
//
#include <hip/hip_runtime.h>
#include <hip/hip_bf16.h>

static constexpr int EDIM = 128;   // embedding size
static constexpr int FIN  = 256;   // input features

typedef __attribute__((ext_vector_type(8))) short bf16x8;
typedef __attribute__((ext_vector_type(4))) float f32x4;

__device__ inline short f2b(float f) {
    __hip_bfloat16 h = __float2bfloat16(f);
    return *reinterpret_cast<short*>(&h);
}

// ---------------------------------------------------------------------------
// Scalars: Aa = a_low + a_mid (coeff on adj part), Bb = b_low - c_mid (on Y)
// ---------------------------------------------------------------------------
__global__ void k_scalars(const float* __restrict__ lg,
                          const float* __restrict__ mg,
                          float* __restrict__ sc) {
    if (threadIdx.x == 0 && blockIdx.x == 0) {
        const float a0 = -1e-9f, a1 = 1.0f + 1e-9f;
        float a_low = 0.f, b_low = 0.f, a_mid = 0.f, c_mid = 0.f;
        for (int i = 0; i < 5; ++i) {
            float l0 = fmaxf(lg[2*i], 0.f), l1 = fmaxf(lg[2*i+1], 0.f);
            a_low += l0 * a0 + l1 * a1;
            b_low += l0 * (1.f - a0) + l1 * (1.f - a1);
            float m0 = fmaxf(mg[2*i], 0.f), m1 = fmaxf(mg[2*i+1], 0.f);
            a_mid += m0 + m1;
            c_mid += m0 * a0 + m1 * a1;
        }
        sc[0] = a_low + a_mid;
        sc[1] = b_low - c_mid;
    }
}

// ---------------------------------------------------------------------------
// Prep: Wt[c][k] = bf16(W[k][c])  (transpose+cast, 32 blocks)
//       vwb[c][k] = bf16(vw[c][k]) (cast, 16 blocks)
// ---------------------------------------------------------------------------
__global__ __launch_bounds__(256) void k_prep(const float* __restrict__ W,
                                              const float* __restrict__ vw,
                                              short* __restrict__ Wt,
                                              short* __restrict__ vwb) {
    const int bid = blockIdx.x, tid = threadIdx.x;
    if (bid < 32) {
        __shared__ float T[32][33];
        int kt = bid >> 2, ct = bid & 3;
        int r = tid >> 3, c4 = (tid & 7) << 2;
        float4 v = *(const float4*)(W + (size_t)(kt*32 + r) * EDIM + ct*32 + c4);
        T[c4+0][r] = v.x; T[c4+1][r] = v.y; T[c4+2][r] = v.z; T[c4+3][r] = v.w;
        __syncthreads();
        int c = tid >> 3, k4 = (tid & 7) << 2;
        short4 s;
        s.x = f2b(T[c][k4+0]); s.y = f2b(T[c][k4+1]);
        s.z = f2b(T[c][k4+2]); s.w = f2b(T[c][k4+3]);
        *(short4*)(Wt + (size_t)(ct*32 + c) * FIN + kt*32 + k4) = s;
    } else {
        int idx = ((bid - 32) * 256 + tid) * 4;     // 16 blocks cover 128*128
        float4 v = *(const float4*)(vw + idx);
        short4 s;
        s.x = f2b(v.x); s.y = f2b(v.y); s.z = f2b(v.z); s.w = f2b(v.w);
        *(short4*)(vwb + idx) = s;
    }
}

// ---------------------------------------------------------------------------
// Fused MFMA GEMM: Y[M,128](bf16) = relu(F[M,256] @ W) @ vw^T
// BM=128, 4 waves; wave w owns rows 32w..32w+31 (2 mblocks x 8 nfrags).
// A-frag: row=lane&15, k=8*(lane>>4)+i ; B-frag: col=lane&15, same k
// D: col=lane&15, row=4*(lane>>4)+i  (m89-verified)
// ---------------------------------------------------------------------------
__global__ __launch_bounds__(256) void k_fused(const float* __restrict__ F,
                                               const short* __restrict__ Wt,
                                               const short* __restrict__ vwb,
                                               short* __restrict__ Yb, int M) {
    __shared__ short Fb[128 * 40];    // F tile 128x32 bf16, pad-40 rows (2-way free)
    __shared__ short Sb[128 * 136];   // sup / Y tile 128x128 bf16, pad-136 rows
    const int tid  = threadIdx.x;
    const int wave = tid >> 6, lane = tid & 63;
    const int l15  = lane & 15, lhi = lane >> 4;
    const int bm   = blockIdx.x * 128;

    f32x4 acc[2][8];
    #pragma unroll
    for (int a = 0; a < 2; ++a)
        #pragma unroll
        for (int b = 0; b < 8; ++b) acc[a][b] = (f32x4){0.f, 0.f, 0.f, 0.f};

    // ---- GEMM1: sup = relu(F @ W), K = 256 in 8 steps of 32 ----
    for (int kt = 0; kt < FIN / 32; ++kt) {
        #pragma unroll
        for (int j = 0; j < 4; ++j) {               // stage F tile (fp32 -> bf16)
            int idx = tid + 256 * j;                // 128 rows x 8 float4
            int r = idx >> 3, c4 = (idx & 7) << 2;
            int gr = bm + r;
            float4 v = make_float4(0.f, 0.f, 0.f, 0.f);
            if (gr < M) v = *(const float4*)(F + (size_t)gr * FIN + kt*32 + c4);
            short4 s;
            s.x = f2b(v.x); s.y = f2b(v.y); s.z = f2b(v.z); s.w = f2b(v.w);
            *(short4*)(&Fb[r * 40 + c4]) = s;
        }
        __syncthreads();
        bf16x8 bf[8];
        #pragma unroll
        for (int nf = 0; nf < 8; ++nf)              // B frags direct from L2
            bf[nf] = *(const bf16x8*)(Wt + (size_t)(nf*16 + l15) * FIN + kt*32 + lhi*8);
        bf16x8 af[2];
        #pragma unroll
        for (int mb = 0; mb < 2; ++mb)
            af[mb] = *(const bf16x8*)(&Fb[(wave*32 + mb*16 + l15) * 40 + lhi*8]);
        #pragma unroll
        for (int mb = 0; mb < 2; ++mb)
            #pragma unroll
            for (int nf = 0; nf < 8; ++nf)
                acc[mb][nf] = __builtin_amdgcn_mfma_f32_16x16x32_bf16(
                    af[mb], bf[nf], acc[mb][nf], 0, 0, 0);
        __syncthreads();
    }

    // ---- relu + bf16 -> Sb (each wave writes its own 32 rows) ----
    #pragma unroll
    for (int mb = 0; mb < 2; ++mb)
        #pragma unroll
        for (int nf = 0; nf < 8; ++nf)
            #pragma unroll
            for (int i = 0; i < 4; ++i) {
                int row = wave*32 + mb*16 + lhi*4 + i;
                Sb[row * 136 + nf*16 + l15] = f2b(fmaxf(acc[mb][nf][i], 0.f));
            }
    __syncthreads();

    // ---- GEMM2: Y = sup @ vw^T, K = 128 in 4 steps ----
    f32x4 acc2[2][8];
    #pragma unroll
    for (int a = 0; a < 2; ++a)
        #pragma unroll
        for (int b = 0; b < 8; ++b) acc2[a][b] = (f32x4){0.f, 0.f, 0.f, 0.f};

    for (int ks = 0; ks < EDIM / 32; ++ks) {
        bf16x8 bf2[8];
        #pragma unroll
        for (int nf = 0; nf < 8; ++nf)
            bf2[nf] = *(const bf16x8*)(vwb + (size_t)(nf*16 + l15) * EDIM + ks*32 + lhi*8);
        bf16x8 af2[2];
        #pragma unroll
        for (int mb = 0; mb < 2; ++mb)
            af2[mb] = *(const bf16x8*)(&Sb[(wave*32 + mb*16 + l15) * 136 + ks*32 + lhi*8]);
        #pragma unroll
        for (int mb = 0; mb < 2; ++mb)
            #pragma unroll
            for (int nf = 0; nf < 8; ++nf)
                acc2[mb][nf] = __builtin_amdgcn_mfma_f32_16x16x32_bf16(
                    af2[mb], bf2[nf], acc2[mb][nf], 0, 0, 0);
    }

    // ---- Y -> Sb (own rows), then coalesced bf16 store ----
    #pragma unroll
    for (int mb = 0; mb < 2; ++mb)
        #pragma unroll
        for (int nf = 0; nf < 8; ++nf)
            #pragma unroll
            for (int i = 0; i < 4; ++i) {
                int row = wave*32 + mb*16 + lhi*4 + i;
                Sb[row * 136 + nf*16 + l15] = f2b(acc2[mb][nf][i]);
            }
    __syncthreads();

    #pragma unroll
    for (int j = 0; j < 8; ++j) {                  // 32 rows x 16 chunks per wave
        int idx = lane + 64 * j;
        int rl = idx >> 4, ch = idx & 15;
        int gr = bm + wave*32 + rl;
        if (gr < M) {
            float4 t = *(const float4*)(&Sb[(wave*32 + rl) * 136 + ch*8]);
            *(float4*)(Yb + (size_t)gr * EDIM + ch*8) = t;
        }
    }
}

// ---------------------------------------------------------------------------
// CSR build: count -> exclusive scan (3 kernels) -> fill packed {col, w}
// ---------------------------------------------------------------------------
__global__ void k_count(const int* __restrict__ ei, int* __restrict__ start, int ne) {
    int e = blockIdx.x * blockDim.x + threadIdx.x;
    if (e < ne) atomicAdd(&start[ei[e]], 1);
}

__global__ void k_scan1(const int* __restrict__ cnt, int* __restrict__ bsum, int n) {
    __shared__ int sh[256];
    int t = threadIdx.x;
    int i = blockIdx.x * 256 + t;
    sh[t] = (i < n) ? cnt[i] : 0;
    __syncthreads();
    for (int s = 128; s > 0; s >>= 1) {
        if (t < s) sh[t] += sh[t + s];
        __syncthreads();
    }
    if (t == 0) bsum[blockIdx.x] = sh[0];
}

__global__ void k_scan2(int* __restrict__ bsum, int nb) {
    __shared__ int sh[256];
    int t = threadIdx.x;
    int v = (t < nb) ? bsum[t] : 0;
    sh[t] = v;
    __syncthreads();
    for (int off = 1; off < 256; off <<= 1) {
        int x = (t >= off) ? sh[t - off] : 0;
        __syncthreads();
        sh[t] += x;
        __syncthreads();
    }
    if (t < nb) bsum[t] = sh[t] - v;   // exclusive
}

__global__ void k_scan3(int* __restrict__ start, const int* __restrict__ bsum, int n) {
    __shared__ int sh[256];
    int t = threadIdx.x;
    int i = blockIdx.x * 256 + t;
    int v = (i < n) ? start[i] : 0;
    sh[t] = v;
    __syncthreads();
    for (int off = 1; off < 256; off <<= 1) {
        int x = (t >= off) ? sh[t - off] : 0;
        __syncthreads();
        sh[t] += x;
        __syncthreads();
    }
    if (i < n) start[i] = sh[t] - v + bsum[blockIdx.x];   // exclusive start
}

__global__ void k_fill(const int* __restrict__ ei, const float* __restrict__ ew,
                       int* __restrict__ start, int2* __restrict__ colw, int ne) {
    int e = blockIdx.x * blockDim.x + threadIdx.x;
    if (e >= ne) return;
    int pos = atomicAdd(&start[ei[e]], 1);   // start[r] ends as end-of-row r
    colw[pos] = make_int2(ei[ne + e], __float_as_int(ew[e]));
}

// ---------------------------------------------------------------------------
// Fused gather + epilogue: out[row] = Aa * sum_e w_e * Y[col_e] + Bb*Y[row] + 2*vb
// ---------------------------------------------------------------------------
__global__ __launch_bounds__(256) void k_gather(const int2* __restrict__ colw,
                                                const int* __restrict__ start,
                                                const __hip_bfloat162* __restrict__ Yb,
                                                const float* __restrict__ vb,
                                                const float* __restrict__ sc,
                                                float* __restrict__ out, int n) {
    int wave = (blockIdx.x * blockDim.x + threadIdx.x) >> 6;
    int lane = threadIdx.x & 63;
    if (wave >= n) return;
    int begin = (wave == 0) ? 0 : start[wave - 1];
    int end   = start[wave];
    const float Aa = sc[0];
    const float Bb = sc[1];

    float2 acc = make_float2(0.f, 0.f);
    for (int base = begin; base < end; base += 64) {
        int m = end - base;
        int2 cw = make_int2(0, 0);
        if (lane < m) cw = colw[base + lane];
        int cnt = (m < 64) ? m : 64;
        for (int j = 0; j < cnt; ++j) {
            int col   = __shfl(cw.x, j);
            float w   = __shfl(__int_as_float(cw.y), j);
            float2 v  = __bfloat1622float2(Yb[(size_t)col * 64 + lane]);
            acc.x = fmaf(w, v.x, acc.x);
            acc.y = fmaf(w, v.y, acc.y);
        }
    }
    float2 y = __bfloat1622float2(Yb[(size_t)wave * 64 + lane]);
    float2 b = *(const float2*)(vb + lane * 2);
    float2 o;
    o.x = fmaf(Aa, acc.x, fmaf(Bb, y.x, 2.f * b.x));
    o.y = fmaf(Aa, acc.y, fmaf(Bb, y.y, 2.f * b.y));
    *(float2*)(out + (size_t)wave * EDIM + lane * 2) = o;
}

// ---------------------------------------------------------------------------
extern "C" void kernel_launch(void* const* d_in, const int* in_sizes, int n_in,
                              void* d_out, int out_size, void* d_ws, size_t ws_size,
                              hipStream_t stream) {
    const float* feature = (const float*)d_in[0];
    const int*   eidx    = (const int*)d_in[1];   // [2, NE] int32
    const float* ew      = (const float*)d_in[2];
    const float* weight  = (const float*)d_in[3];
    const float* lg      = (const float*)d_in[4];
    const float* mg      = (const float*)d_in[5];
    // d_in[6..9] = q_w,q_b,k_w,k_b provably unused: softmax over the query axis
    // followed by sum over the query axis makes each k-column of w sum to 1.
    const float* vw      = (const float*)d_in[10];
    const float* vb      = (const float*)d_in[11];
    float* out = (float*)d_out;

    const int M  = in_sizes[0] / FIN;   // 50000
    const int NE = in_sizes[2];         // 600000

    // workspace layout (~18 MB)
    char* ws = (char*)d_ws;
    short* Yb   = (short*)ws;                                   // M*128*2 = 12.8 MB
    char* p = ws + (size_t)M * EDIM * 2;
    int2*  colw = (int2*)p;          p += (size_t)NE * 8;       // 4.8 MB
    int*   start = (int*)p;          p += (size_t)M * 4;        // 200 KB
    int*   bsum = (int*)p;           p += 256 * 4;
    short* Wt   = (short*)p;         p += (size_t)EDIM * FIN * 2;  // 64 KB
    short* vwb  = (short*)p;         p += (size_t)EDIM * EDIM * 2; // 32 KB
    float* sc   = (float*)p;

    const int nb = (M + 255) / 256;

    k_scalars<<<1, 64, 0, stream>>>(lg, mg, sc);
    hipMemsetAsync(start, 0, (size_t)M * 4, stream);
    k_prep<<<48, 256, 0, stream>>>(weight, vw, Wt, vwb);

    int gFused = (M + 127) / 128;
    k_fused<<<gFused, 256, 0, stream>>>(feature, Wt, vwb, Yb, M);

    int gE = (NE + 255) / 256;
    k_count<<<gE, 256, 0, stream>>>(eidx, start, NE);
    k_scan1<<<nb, 256, 0, stream>>>(start, bsum, M);
    k_scan2<<<1, 256, 0, stream>>>(bsum, nb);
    k_scan3<<<nb, 256, 0, stream>>>(start, bsum, M);
    k_fill<<<gE, 256, 0, stream>>>(eidx, ew, start, colw, NE);

    int gGather = ((M * 64) + 255) / 256;     // one wave per row
    k_gather<<<gGather, 256, 0, stream>>>(colw, start, (const __hip_bfloat162*)Yb,
                                          vb, sc, out, M);
}

// Round 5
// 165.386 us; speedup vs baseline: 3.6372x; 1.0005x over previous
//
#include <hip/hip_runtime.h>
#include <hip/hip_bf16.h>

static constexpr int EDIM = 128;   // embedding size
static constexpr int FIN  = 256;   // input features

typedef __attribute__((ext_vector_type(8))) short bf16x8;
typedef __attribute__((ext_vector_type(4))) float f32x4;

__device__ inline short f2b(float f) {
    __hip_bfloat16 h = __float2bfloat16(f);
    return *reinterpret_cast<short*>(&h);
}

// ---------------------------------------------------------------------------
// Scalars: Aa = a_low + a_mid (coeff on adj part), Bb = b_low - c_mid (on Y)
// ---------------------------------------------------------------------------
__global__ void k_scalars(const float* __restrict__ lg,
                          const float* __restrict__ mg,
                          float* __restrict__ sc) {
    if (threadIdx.x == 0 && blockIdx.x == 0) {
        const float a0 = -1e-9f, a1 = 1.0f + 1e-9f;
        float a_low = 0.f, b_low = 0.f, a_mid = 0.f, c_mid = 0.f;
        for (int i = 0; i < 5; ++i) {
            float l0 = fmaxf(lg[2*i], 0.f), l1 = fmaxf(lg[2*i+1], 0.f);
            a_low += l0 * a0 + l1 * a1;
            b_low += l0 * (1.f - a0) + l1 * (1.f - a1);
            float m0 = fmaxf(mg[2*i], 0.f), m1 = fmaxf(mg[2*i+1], 0.f);
            a_mid += m0 + m1;
            c_mid += m0 * a0 + m1 * a1;
        }
        sc[0] = a_low + a_mid;
        sc[1] = b_low - c_mid;
    }
}

// ---------------------------------------------------------------------------
// Prep: Wt[c][k] = bf16(W[k][c])  (transpose+cast, 32 blocks)
//       vwb[c][k] = bf16(vw[c][k]) (cast, 16 blocks)
// ---------------------------------------------------------------------------
__global__ __launch_bounds__(256) void k_prep(const float* __restrict__ W,
                                              const float* __restrict__ vw,
                                              short* __restrict__ Wt,
                                              short* __restrict__ vwb) {
    const int bid = blockIdx.x, tid = threadIdx.x;
    if (bid < 32) {
        __shared__ float T[32][33];
        int kt = bid >> 2, ct = bid & 3;
        int r = tid >> 3, c4 = (tid & 7) << 2;
        float4 v = *(const float4*)(W + (size_t)(kt*32 + r) * EDIM + ct*32 + c4);
        T[c4+0][r] = v.x; T[c4+1][r] = v.y; T[c4+2][r] = v.z; T[c4+3][r] = v.w;
        __syncthreads();
        int c = tid >> 3, k4 = (tid & 7) << 2;
        short4 s;
        s.x = f2b(T[c][k4+0]); s.y = f2b(T[c][k4+1]);
        s.z = f2b(T[c][k4+2]); s.w = f2b(T[c][k4+3]);
        *(short4*)(Wt + (size_t)(ct*32 + c) * FIN + kt*32 + k4) = s;
    } else {
        int idx = ((bid - 32) * 256 + tid) * 4;     // 16 blocks cover 128*128
        float4 v = *(const float4*)(vw + idx);
        short4 s;
        s.x = f2b(v.x); s.y = f2b(v.y); s.z = f2b(v.z); s.w = f2b(v.w);
        *(short4*)(vwb + idx) = s;
    }
}

// ---------------------------------------------------------------------------
// Fused MFMA GEMM: Y[M,128](bf16) = relu(F[M,256] @ W) @ vw^T
// BM=64, 4 independent waves, wave owns 16 rows. NO syncthreads (LDS is
// per-wave-private). A-frags for GEMM1 come straight from global F.
// Frag maps (m89-verified): A row=lane&15, k=8*(lane>>4)+i ; B col=lane&15;
// D col=lane&15, row=4*(lane>>4)+i.
// ---------------------------------------------------------------------------
__global__ __launch_bounds__(256) void k_fused(const float* __restrict__ F,
                                               const short* __restrict__ Wt,
                                               const short* __restrict__ vwb,
                                               short* __restrict__ Yb, int M) {
    __shared__ short Sb[64 * 136];    // per-wave 16x136 slab (stride 272B: conflict-free b128)
    const int tid  = threadIdx.x;
    const int wave = tid >> 6, lane = tid & 63;
    const int l15  = lane & 15, lhi = lane >> 4;
    const int bm   = blockIdx.x * 64;
    const int wrow = wave * 16;                    // wave's row offset in tile

    // ---- GEMM1: sup = relu(F @ W), K = 256 in 8 steps of 32, no LDS ----
    f32x4 acc[8];
    #pragma unroll
    for (int b = 0; b < 8; ++b) acc[b] = (f32x4){0.f, 0.f, 0.f, 0.f};

    const int gr_a = bm + wrow + l15;              // row this lane's A-frag covers
    const bool va  = gr_a < M;
    const float* fp = F + (size_t)(va ? gr_a : 0) * FIN + lhi * 8;

    #pragma unroll 2
    for (int kt = 0; kt < FIN / 32; ++kt) {
        float4 a0 = make_float4(0.f,0.f,0.f,0.f), a1 = a0;
        if (va) {
            a0 = *(const float4*)(fp + kt*32);
            a1 = *(const float4*)(fp + kt*32 + 4);
        }
        bf16x8 af;
        af[0]=f2b(a0.x); af[1]=f2b(a0.y); af[2]=f2b(a0.z); af[3]=f2b(a0.w);
        af[4]=f2b(a1.x); af[5]=f2b(a1.y); af[6]=f2b(a1.z); af[7]=f2b(a1.w);
        #pragma unroll
        for (int nf = 0; nf < 8; ++nf) {
            bf16x8 bf = *(const bf16x8*)(Wt + (size_t)(nf*16 + l15) * FIN + kt*32 + lhi*8);
            acc[nf] = __builtin_amdgcn_mfma_f32_16x16x32_bf16(af, bf, acc[nf], 0, 0, 0);
        }
    }

    // ---- relu + bf16 -> Sb (wave-private transpose slab) ----
    #pragma unroll
    for (int nf = 0; nf < 8; ++nf)
        #pragma unroll
        for (int i = 0; i < 4; ++i)
            Sb[(wrow + lhi*4 + i) * 136 + nf*16 + l15] = f2b(fmaxf(acc[nf][i], 0.f));

    // ---- GEMM2: Y = sup @ vw^T, K = 128 in 4 steps ----
    f32x4 acc2[8];
    #pragma unroll
    for (int b = 0; b < 8; ++b) acc2[b] = (f32x4){0.f, 0.f, 0.f, 0.f};

    #pragma unroll
    for (int ks = 0; ks < EDIM / 32; ++ks) {
        bf16x8 af2 = *(const bf16x8*)(&Sb[(wrow + l15) * 136 + ks*32 + lhi*8]);
        #pragma unroll
        for (int nf = 0; nf < 8; ++nf) {
            bf16x8 bf2 = *(const bf16x8*)(vwb + (size_t)(nf*16 + l15) * EDIM + ks*32 + lhi*8);
            acc2[nf] = __builtin_amdgcn_mfma_f32_16x16x32_bf16(af2, bf2, acc2[nf], 0, 0, 0);
        }
    }

    // ---- Y -> Sb (same slab), then coalesced bf16 store ----
    #pragma unroll
    for (int nf = 0; nf < 8; ++nf)
        #pragma unroll
        for (int i = 0; i < 4; ++i)
            Sb[(wrow + lhi*4 + i) * 136 + nf*16 + l15] = f2b(acc2[nf][i]);

    const int srow = lane >> 2;                    // 16 rows, 4 lanes each
    const int sch  = (lane & 3) * 32;              // 32-col (64B) chunk
    const int gr_s = bm + wrow + srow;
    if (gr_s < M) {
        #pragma unroll
        for (int r = 0; r < 4; ++r) {
            float4 t = *(const float4*)(&Sb[(wrow + srow) * 136 + sch + r*8]);
            *(float4*)(Yb + (size_t)gr_s * EDIM + sch + r*8) = t;
        }
    }
}

// ---------------------------------------------------------------------------
// CSR build: count -> exclusive scan (3 kernels) -> fill packed {col, w}
// ---------------------------------------------------------------------------
__global__ void k_count(const int* __restrict__ ei, int* __restrict__ start, int ne) {
    int e = blockIdx.x * blockDim.x + threadIdx.x;
    if (e < ne) atomicAdd(&start[ei[e]], 1);
}

__global__ void k_scan1(const int* __restrict__ cnt, int* __restrict__ bsum, int n) {
    __shared__ int sh[256];
    int t = threadIdx.x;
    int i = blockIdx.x * 256 + t;
    sh[t] = (i < n) ? cnt[i] : 0;
    __syncthreads();
    for (int s = 128; s > 0; s >>= 1) {
        if (t < s) sh[t] += sh[t + s];
        __syncthreads();
    }
    if (t == 0) bsum[blockIdx.x] = sh[0];
}

__global__ void k_scan2(int* __restrict__ bsum, int nb) {
    __shared__ int sh[256];
    int t = threadIdx.x;
    int v = (t < nb) ? bsum[t] : 0;
    sh[t] = v;
    __syncthreads();
    for (int off = 1; off < 256; off <<= 1) {
        int x = (t >= off) ? sh[t - off] : 0;
        __syncthreads();
        sh[t] += x;
        __syncthreads();
    }
    if (t < nb) bsum[t] = sh[t] - v;   // exclusive
}

__global__ void k_scan3(int* __restrict__ start, const int* __restrict__ bsum, int n) {
    __shared__ int sh[256];
    int t = threadIdx.x;
    int i = blockIdx.x * 256 + t;
    int v = (i < n) ? start[i] : 0;
    sh[t] = v;
    __syncthreads();
    for (int off = 1; off < 256; off <<= 1) {
        int x = (t >= off) ? sh[t - off] : 0;
        __syncthreads();
        sh[t] += x;
        __syncthreads();
    }
    if (i < n) start[i] = sh[t] - v + bsum[blockIdx.x];   // exclusive start
}

__global__ void k_fill(const int* __restrict__ ei, const float* __restrict__ ew,
                       int* __restrict__ start, int2* __restrict__ colw, int ne) {
    int e = blockIdx.x * blockDim.x + threadIdx.x;
    if (e >= ne) return;
    int pos = atomicAdd(&start[ei[e]], 1);   // start[r] ends as end-of-row r
    colw[pos] = make_int2(ei[ne + e], __float_as_int(ew[e]));
}

// ---------------------------------------------------------------------------
// Fused gather + epilogue: out[row] = Aa * sum_e w_e * Y[col_e] + Bb*Y[row] + 2*vb
// One wave per row; 4-way unrolled edge loop for load-level parallelism.
// ---------------------------------------------------------------------------
__global__ __launch_bounds__(256) void k_gather(const int2* __restrict__ colw,
                                                const int* __restrict__ start,
                                                const __hip_bfloat162* __restrict__ Yb,
                                                const float* __restrict__ vb,
                                                const float* __restrict__ sc,
                                                float* __restrict__ out, int n) {
    int wave = (blockIdx.x * blockDim.x + threadIdx.x) >> 6;
    int lane = threadIdx.x & 63;
    if (wave >= n) return;
    int begin = (wave == 0) ? 0 : start[wave - 1];
    int end   = start[wave];
    const float Aa = sc[0];
    const float Bb = sc[1];

    float2 acc = make_float2(0.f, 0.f);
    for (int base = begin; base < end; base += 64) {
        int m = end - base;
        if (m > 64) m = 64;
        int2 cw = make_int2(0, 0);
        if (lane < m) cw = colw[base + lane];
        int j = 0;
        for (; j + 4 <= m; j += 4) {
            int   c0 = __shfl(cw.x, j+0), c1 = __shfl(cw.x, j+1),
                  c2 = __shfl(cw.x, j+2), c3 = __shfl(cw.x, j+3);
            float w0 = __shfl(__int_as_float(cw.y), j+0),
                  w1 = __shfl(__int_as_float(cw.y), j+1),
                  w2 = __shfl(__int_as_float(cw.y), j+2),
                  w3 = __shfl(__int_as_float(cw.y), j+3);
            float2 v0 = __bfloat1622float2(Yb[(size_t)c0 * 64 + lane]);
            float2 v1 = __bfloat1622float2(Yb[(size_t)c1 * 64 + lane]);
            float2 v2 = __bfloat1622float2(Yb[(size_t)c2 * 64 + lane]);
            float2 v3 = __bfloat1622float2(Yb[(size_t)c3 * 64 + lane]);
            acc.x = fmaf(w0, v0.x, acc.x); acc.y = fmaf(w0, v0.y, acc.y);
            acc.x = fmaf(w1, v1.x, acc.x); acc.y = fmaf(w1, v1.y, acc.y);
            acc.x = fmaf(w2, v2.x, acc.x); acc.y = fmaf(w2, v2.y, acc.y);
            acc.x = fmaf(w3, v3.x, acc.x); acc.y = fmaf(w3, v3.y, acc.y);
        }
        for (; j < m; ++j) {
            int   col = __shfl(cw.x, j);
            float w   = __shfl(__int_as_float(cw.y), j);
            float2 v  = __bfloat1622float2(Yb[(size_t)col * 64 + lane]);
            acc.x = fmaf(w, v.x, acc.x);
            acc.y = fmaf(w, v.y, acc.y);
        }
    }
    float2 y = __bfloat1622float2(Yb[(size_t)wave * 64 + lane]);
    float2 b = *(const float2*)(vb + lane * 2);
    float2 o;
    o.x = fmaf(Aa, acc.x, fmaf(Bb, y.x, 2.f * b.x));
    o.y = fmaf(Aa, acc.y, fmaf(Bb, y.y, 2.f * b.y));
    *(float2*)(out + (size_t)wave * EDIM + lane * 2) = o;
}

// ---------------------------------------------------------------------------
extern "C" void kernel_launch(void* const* d_in, const int* in_sizes, int n_in,
                              void* d_out, int out_size, void* d_ws, size_t ws_size,
                              hipStream_t stream) {
    const float* feature = (const float*)d_in[0];
    const int*   eidx    = (const int*)d_in[1];   // [2, NE] int32
    const float* ew      = (const float*)d_in[2];
    const float* weight  = (const float*)d_in[3];
    const float* lg      = (const float*)d_in[4];
    const float* mg      = (const float*)d_in[5];
    // d_in[6..9] = q_w,q_b,k_w,k_b provably unused: softmax over the query axis
    // followed by sum over the query axis makes each k-column of w sum to 1.
    const float* vw      = (const float*)d_in[10];
    const float* vb      = (const float*)d_in[11];
    float* out = (float*)d_out;

    const int M  = in_sizes[0] / FIN;   // 50000
    const int NE = in_sizes[2];         // 600000

    // workspace layout (~18 MB)
    char* ws = (char*)d_ws;
    short* Yb   = (short*)ws;                                   // M*128*2 = 12.8 MB
    char* p = ws + (size_t)M * EDIM * 2;
    int2*  colw = (int2*)p;          p += (size_t)NE * 8;       // 4.8 MB
    int*   start = (int*)p;          p += (size_t)M * 4;        // 200 KB
    int*   bsum = (int*)p;           p += 256 * 4;
    short* Wt   = (short*)p;         p += (size_t)EDIM * FIN * 2;  // 64 KB
    short* vwb  = (short*)p;         p += (size_t)EDIM * EDIM * 2; // 32 KB
    float* sc   = (float*)p;

    const int nb = (M + 255) / 256;

    k_scalars<<<1, 64, 0, stream>>>(lg, mg, sc);
    hipMemsetAsync(start, 0, (size_t)M * 4, stream);
    k_prep<<<48, 256, 0, stream>>>(weight, vw, Wt, vwb);

    int gFused = (M + 63) / 64;
    k_fused<<<gFused, 256, 0, stream>>>(feature, Wt, vwb, Yb, M);

    int gE = (NE + 255) / 256;
    k_count<<<gE, 256, 0, stream>>>(eidx, start, NE);
    k_scan1<<<nb, 256, 0, stream>>>(start, bsum, M);
    k_scan2<<<1, 256, 0, stream>>>(bsum, nb);
    k_scan3<<<nb, 256, 0, stream>>>(start, bsum, M);
    k_fill<<<gE, 256, 0, stream>>>(eidx, ew, start, colw, NE);

    int gGather = ((M * 64) + 255) / 256;     // one wave per row
    k_gather<<<gGather, 256, 0, stream>>>(colw, start, (const __hip_bfloat162*)Yb,
                                          vb, sc, out, M);
}

// Round 6
// 133.099 us; speedup vs baseline: 4.5195x; 1.2426x over previous
//
#include <hip/hip_runtime.h>
#include <hip/hip_bf16.h>

static constexpr int EDIM = 128;   // embedding size
static constexpr int FIN  = 256;   // input features

typedef __attribute__((ext_vector_type(8))) short bf16x8;
typedef __attribute__((ext_vector_type(4))) float f32x4;

__device__ inline short f2b(float f) {
    __hip_bfloat16 h = __float2bfloat16(f);
    return *reinterpret_cast<short*>(&h);
}

// ---------------------------------------------------------------------------
// Prep (one kernel): bid<32  : Wt[c][k] = bf16(W[k][c])   (transpose+cast)
//                    bid<48  : vwb = bf16(vw)
//                    bid==48 : scalar coefficients
//                    bid>48  : zero the CSR 'start' array (replaces memset)
// ---------------------------------------------------------------------------
__global__ __launch_bounds__(256) void k_prep(const float* __restrict__ W,
                                              const float* __restrict__ vw,
                                              const float* __restrict__ lg,
                                              const float* __restrict__ mg,
                                              short* __restrict__ Wt,
                                              short* __restrict__ vwb,
                                              float* __restrict__ sc,
                                              int* __restrict__ start, int M) {
    const int bid = blockIdx.x, tid = threadIdx.x;
    if (bid < 32) {
        __shared__ float T[32][33];
        int kt = bid >> 2, ct = bid & 3;
        int r = tid >> 3, c4 = (tid & 7) << 2;
        float4 v = *(const float4*)(W + (size_t)(kt*32 + r) * EDIM + ct*32 + c4);
        T[c4+0][r] = v.x; T[c4+1][r] = v.y; T[c4+2][r] = v.z; T[c4+3][r] = v.w;
        __syncthreads();
        int c = tid >> 3, k4 = (tid & 7) << 2;
        short4 s;
        s.x = f2b(T[c][k4+0]); s.y = f2b(T[c][k4+1]);
        s.z = f2b(T[c][k4+2]); s.w = f2b(T[c][k4+3]);
        *(short4*)(Wt + (size_t)(ct*32 + c) * FIN + kt*32 + k4) = s;
    } else if (bid < 48) {
        int idx = ((bid - 32) * 256 + tid) * 4;     // 16 blocks cover 128*128
        float4 v = *(const float4*)(vw + idx);
        short4 s;
        s.x = f2b(v.x); s.y = f2b(v.y); s.z = f2b(v.z); s.w = f2b(v.w);
        *(short4*)(vwb + idx) = s;
    } else if (bid == 48) {
        if (tid == 0) {
            const float a0 = -1e-9f, a1 = 1.0f + 1e-9f;
            float a_low = 0.f, b_low = 0.f, a_mid = 0.f, c_mid = 0.f;
            for (int i = 0; i < 5; ++i) {
                float l0 = fmaxf(lg[2*i], 0.f), l1 = fmaxf(lg[2*i+1], 0.f);
                a_low += l0 * a0 + l1 * a1;
                b_low += l0 * (1.f - a0) + l1 * (1.f - a1);
                float m0 = fmaxf(mg[2*i], 0.f), m1 = fmaxf(mg[2*i+1], 0.f);
                a_mid += m0 + m1;
                c_mid += m0 * a0 + m1 * a1;
            }
            sc[0] = a_low + a_mid;
            sc[1] = b_low - c_mid;
        }
    } else {
        int i = (bid - 49) * 256 + tid;
        if (i < M) start[i] = 0;
    }
}

// ---------------------------------------------------------------------------
// Fused MFMA GEMM: Y[M,128](bf16) = relu(F[M,256] @ W) @ vw^T
// 512 threads (8 waves), BM=128, wave owns 16 rows.
// Wt (64KB) + vwb (32KB) staged in LDS once, XOR-swizzled 16B chunks so the
// 512B-row-stride fragment reads hit all 32 banks (2-way = free).
// All 16 F float4 loads per lane are issued upfront (pure ILP latency hiding;
// occupancy is 1 block/CU due to 133KB LDS).
// Frag maps (m89-verified): A row=lane&15, k=8*(lane>>4)+i ; B col=lane&15;
// D col=lane&15, row=4*(lane>>4)+i.
// ---------------------------------------------------------------------------
__global__ __launch_bounds__(512) void k_fused(const float* __restrict__ F,
                                               const short* __restrict__ Wt,
                                               const short* __restrict__ vwb,
                                               short* __restrict__ Yb, int M) {
    __shared__ short WtL[32768];     // 64KB, rows of 256 shorts (32 x 16B chunks)
    __shared__ short vwL[16384];     // 32KB, rows of 128 shorts (16 x 16B chunks)
    __shared__ short Sb[128 * 136];  // 34.8KB wave-private transpose slabs

    const int tid  = threadIdx.x;
    const int wave = tid >> 6, lane = tid & 63;
    const int l15  = lane & 15, lhi = lane >> 4;
    const int bm   = blockIdx.x * 128;
    const int wrow = wave * 16;
    const int swz  = l15 & 7;                      // row-derived XOR for frags

    // ---- issue ALL F loads for this lane's A-row (64 VGPRs, deep ILP) ----
    const int gr_a = bm + wrow + l15;
    const bool va  = gr_a < M;
    const float* fp = F + (size_t)(va ? gr_a : 0) * FIN + lhi * 8;
    float4 fa[16];
    #pragma unroll
    for (int t = 0; t < 16; ++t) {
        fa[t] = make_float4(0.f, 0.f, 0.f, 0.f);
        if (va) fa[t] = *(const float4*)(fp + (t >> 1) * 32 + (t & 1) * 4);
    }

    // ---- stage Wt: 4096 16B chunks, swizzled; coalesced global reads ----
    #pragma unroll
    for (int i = 0; i < 8; ++i) {
        int idx = tid + i * 512;                   // 0..4095
        int r = idx >> 5, c = idx & 31;
        int4 v = *(const int4*)(Wt + r * 256 + c * 8);
        *(int4*)(&WtL[r * 256 + ((c ^ (r & 7)) << 3)]) = v;
    }
    // ---- stage vwb: 2048 chunks ----
    #pragma unroll
    for (int i = 0; i < 4; ++i) {
        int idx = tid + i * 512;                   // 0..2047
        int r = idx >> 4, c = idx & 15;
        int4 v = *(const int4*)(vwb + r * 128 + c * 8);
        *(int4*)(&vwL[r * 128 + ((c ^ (r & 7)) << 3)]) = v;
    }
    __syncthreads();

    // ---- GEMM1: sup = relu(F @ W), K = 256 in 8 steps of 32, B from LDS ----
    f32x4 acc[8];
    #pragma unroll
    for (int b = 0; b < 8; ++b) acc[b] = (f32x4){0.f, 0.f, 0.f, 0.f};

    #pragma unroll
    for (int kt = 0; kt < 8; ++kt) {
        float4 a0 = fa[kt*2], a1 = fa[kt*2 + 1];
        bf16x8 af;
        af[0]=f2b(a0.x); af[1]=f2b(a0.y); af[2]=f2b(a0.z); af[3]=f2b(a0.w);
        af[4]=f2b(a1.x); af[5]=f2b(a1.y); af[6]=f2b(a1.z); af[7]=f2b(a1.w);
        #pragma unroll
        for (int nf = 0; nf < 8; ++nf) {
            bf16x8 bf = *(const bf16x8*)(&WtL[(nf*16 + l15) * 256 +
                                              (((kt*4 + lhi) ^ swz) << 3)]);
            acc[nf] = __builtin_amdgcn_mfma_f32_16x16x32_bf16(af, bf, acc[nf], 0, 0, 0);
        }
    }

    // ---- relu + bf16 -> wave-private slab (transpose D->A layout) ----
    #pragma unroll
    for (int nf = 0; nf < 8; ++nf)
        #pragma unroll
        for (int i = 0; i < 4; ++i)
            Sb[(wrow + lhi*4 + i) * 136 + nf*16 + l15] = f2b(fmaxf(acc[nf][i], 0.f));

    // ---- GEMM2: Y = sup @ vw^T, K = 128 in 4 steps, all LDS ----
    f32x4 acc2[8];
    #pragma unroll
    for (int b = 0; b < 8; ++b) acc2[b] = (f32x4){0.f, 0.f, 0.f, 0.f};

    #pragma unroll
    for (int ks = 0; ks < 4; ++ks) {
        bf16x8 af2 = *(const bf16x8*)(&Sb[(wrow + l15) * 136 + ks*32 + lhi*8]);
        #pragma unroll
        for (int nf = 0; nf < 8; ++nf) {
            bf16x8 bf2 = *(const bf16x8*)(&vwL[(nf*16 + l15) * 128 +
                                               (((ks*4 + lhi) ^ swz) << 3)]);
            acc2[nf] = __builtin_amdgcn_mfma_f32_16x16x32_bf16(af2, bf2, acc2[nf], 0, 0, 0);
        }
    }

    // ---- Y -> slab (same wave-private rows), then coalesced store ----
    #pragma unroll
    for (int nf = 0; nf < 8; ++nf)
        #pragma unroll
        for (int i = 0; i < 4; ++i)
            Sb[(wrow + lhi*4 + i) * 136 + nf*16 + l15] = f2b(acc2[nf][i]);

    const int srow = lane >> 2;                    // 16 rows, 4 lanes each
    const int sch  = (lane & 3) * 32;              // 64B chunk of the row
    const int gr_s = bm + wrow + srow;
    if (gr_s < M) {
        #pragma unroll
        for (int r = 0; r < 4; ++r) {
            float4 t = *(const float4*)(&Sb[(wrow + srow) * 136 + sch + r*8]);
            *(float4*)(Yb + (size_t)gr_s * EDIM + sch + r*8) = t;
        }
    }
}

// ---------------------------------------------------------------------------
// CSR build: count -> exclusive scan (3 kernels) -> fill packed {col, w}
// ---------------------------------------------------------------------------
__global__ void k_count(const int* __restrict__ ei, int* __restrict__ start, int ne) {
    int e = blockIdx.x * blockDim.x + threadIdx.x;
    if (e < ne) atomicAdd(&start[ei[e]], 1);
}

__global__ void k_scan1(const int* __restrict__ cnt, int* __restrict__ bsum, int n) {
    __shared__ int sh[256];
    int t = threadIdx.x;
    int i = blockIdx.x * 256 + t;
    sh[t] = (i < n) ? cnt[i] : 0;
    __syncthreads();
    for (int s = 128; s > 0; s >>= 1) {
        if (t < s) sh[t] += sh[t + s];
        __syncthreads();
    }
    if (t == 0) bsum[blockIdx.x] = sh[0];
}

__global__ void k_scan2(int* __restrict__ bsum, int nb) {
    __shared__ int sh[256];
    int t = threadIdx.x;
    int v = (t < nb) ? bsum[t] : 0;
    sh[t] = v;
    __syncthreads();
    for (int off = 1; off < 256; off <<= 1) {
        int x = (t >= off) ? sh[t - off] : 0;
        __syncthreads();
        sh[t] += x;
        __syncthreads();
    }
    if (t < nb) bsum[t] = sh[t] - v;   // exclusive
}

__global__ void k_scan3(int* __restrict__ start, const int* __restrict__ bsum, int n) {
    __shared__ int sh[256];
    int t = threadIdx.x;
    int i = blockIdx.x * 256 + t;
    int v = (i < n) ? start[i] : 0;
    sh[t] = v;
    __syncthreads();
    for (int off = 1; off < 256; off <<= 1) {
        int x = (t >= off) ? sh[t - off] : 0;
        __syncthreads();
        sh[t] += x;
        __syncthreads();
    }
    if (i < n) start[i] = sh[t] - v + bsum[blockIdx.x];   // exclusive start
}

__global__ void k_fill(const int* __restrict__ ei, const float* __restrict__ ew,
                       int* __restrict__ start, int2* __restrict__ colw, int ne) {
    int e = blockIdx.x * blockDim.x + threadIdx.x;
    if (e >= ne) return;
    int pos = atomicAdd(&start[ei[e]], 1);   // start[r] ends as end-of-row r
    colw[pos] = make_int2(ei[ne + e], __float_as_int(ew[e]));
}

// ---------------------------------------------------------------------------
// Fused gather + epilogue: out[row] = Aa * sum_e w_e * Y[col_e] + Bb*Y[row] + 2*vb
// One wave per row. colw entries read via wave-uniform broadcast loads
// (no per-edge shfl chain); 4-way unrolled for load-level parallelism.
// ---------------------------------------------------------------------------
__global__ __launch_bounds__(256) void k_gather(const int2* __restrict__ colw,
                                                const int* __restrict__ start,
                                                const __hip_bfloat162* __restrict__ Yb,
                                                const float* __restrict__ vb,
                                                const float* __restrict__ sc,
                                                float* __restrict__ out, int n) {
    int wave = (blockIdx.x * blockDim.x + threadIdx.x) >> 6;
    int lane = threadIdx.x & 63;
    if (wave >= n) return;
    int begin = __builtin_amdgcn_readfirstlane((wave == 0) ? 0 : start[wave - 1]);
    int end   = __builtin_amdgcn_readfirstlane(start[wave]);
    const float Aa = sc[0];
    const float Bb = sc[1];

    float2 acc = make_float2(0.f, 0.f);
    int j = begin;
    for (; j + 4 <= end; j += 4) {
        int2 e0 = colw[j+0], e1 = colw[j+1], e2 = colw[j+2], e3 = colw[j+3];
        float2 v0 = __bfloat1622float2(Yb[(size_t)e0.x * 64 + lane]);
        float2 v1 = __bfloat1622float2(Yb[(size_t)e1.x * 64 + lane]);
        float2 v2 = __bfloat1622float2(Yb[(size_t)e2.x * 64 + lane]);
        float2 v3 = __bfloat1622float2(Yb[(size_t)e3.x * 64 + lane]);
        float w0 = __int_as_float(e0.y), w1 = __int_as_float(e1.y);
        float w2 = __int_as_float(e2.y), w3 = __int_as_float(e3.y);
        acc.x = fmaf(w0, v0.x, acc.x); acc.y = fmaf(w0, v0.y, acc.y);
        acc.x = fmaf(w1, v1.x, acc.x); acc.y = fmaf(w1, v1.y, acc.y);
        acc.x = fmaf(w2, v2.x, acc.x); acc.y = fmaf(w2, v2.y, acc.y);
        acc.x = fmaf(w3, v3.x, acc.x); acc.y = fmaf(w3, v3.y, acc.y);
    }
    for (; j < end; ++j) {
        int2 e = colw[j];
        float w = __int_as_float(e.y);
        float2 v = __bfloat1622float2(Yb[(size_t)e.x * 64 + lane]);
        acc.x = fmaf(w, v.x, acc.x);
        acc.y = fmaf(w, v.y, acc.y);
    }
    float2 y = __bfloat1622float2(Yb[(size_t)wave * 64 + lane]);
    float2 b = *(const float2*)(vb + lane * 2);
    float2 o;
    o.x = fmaf(Aa, acc.x, fmaf(Bb, y.x, 2.f * b.x));
    o.y = fmaf(Aa, acc.y, fmaf(Bb, y.y, 2.f * b.y));
    *(float2*)(out + (size_t)wave * EDIM + lane * 2) = o;
}

// ---------------------------------------------------------------------------
extern "C" void kernel_launch(void* const* d_in, const int* in_sizes, int n_in,
                              void* d_out, int out_size, void* d_ws, size_t ws_size,
                              hipStream_t stream) {
    const float* feature = (const float*)d_in[0];
    const int*   eidx    = (const int*)d_in[1];   // [2, NE] int32
    const float* ew      = (const float*)d_in[2];
    const float* weight  = (const float*)d_in[3];
    const float* lg      = (const float*)d_in[4];
    const float* mg      = (const float*)d_in[5];
    // d_in[6..9] = q_w,q_b,k_w,k_b provably unused: softmax over the query axis
    // followed by sum over the query axis makes each k-column of w sum to 1.
    const float* vw      = (const float*)d_in[10];
    const float* vb      = (const float*)d_in[11];
    float* out = (float*)d_out;

    const int M  = in_sizes[0] / FIN;   // 50000
    const int NE = in_sizes[2];         // 600000

    // workspace layout (~18 MB)
    char* ws = (char*)d_ws;
    short* Yb   = (short*)ws;                                   // M*128*2 = 12.8 MB
    char* p = ws + (size_t)M * EDIM * 2;
    int2*  colw = (int2*)p;          p += (size_t)NE * 8;       // 4.8 MB
    int*   start = (int*)p;          p += (size_t)M * 4;        // 200 KB
    int*   bsum = (int*)p;           p += 256 * 4;
    short* Wt   = (short*)p;         p += (size_t)EDIM * FIN * 2;  // 64 KB
    short* vwb  = (short*)p;         p += (size_t)EDIM * EDIM * 2; // 32 KB
    float* sc   = (float*)p;

    const int nb = (M + 255) / 256;           // 196 scan blocks (<=256)

    k_prep<<<49 + nb, 256, 0, stream>>>(weight, vw, lg, mg, Wt, vwb, sc, start, M);

    int gFused = (M + 127) / 128;
    k_fused<<<gFused, 512, 0, stream>>>(feature, Wt, vwb, Yb, M);

    int gE = (NE + 255) / 256;
    k_count<<<gE, 256, 0, stream>>>(eidx, start, NE);
    k_scan1<<<nb, 256, 0, stream>>>(start, bsum, M);
    k_scan2<<<1, 256, 0, stream>>>(bsum, nb);
    k_scan3<<<nb, 256, 0, stream>>>(start, bsum, M);
    k_fill<<<gE, 256, 0, stream>>>(eidx, ew, start, colw, NE);

    int gGather = ((M * 64) + 255) / 256;     // one wave per row
    k_gather<<<gGather, 256, 0, stream>>>(colw, start, (const __hip_bfloat162*)Yb,
                                          vb, sc, out, M);
}

// Round 7
// 126.972 us; speedup vs baseline: 4.7376x; 1.0483x over previous
//
#include <hip/hip_runtime.h>
#include <hip/hip_bf16.h>

static constexpr int EDIM = 128;   // embedding size
static constexpr int FIN  = 256;   // input features

typedef __attribute__((ext_vector_type(8))) short bf16x8;
typedef __attribute__((ext_vector_type(4))) float f32x4;

__device__ inline short f2b(float f) {
    __hip_bfloat16 h = __float2bfloat16(f);
    return *reinterpret_cast<short*>(&h);
}

// ---------------------------------------------------------------------------
// Prep (one kernel): bid<32  : Wt[c][k] = bf16(W[k][c])   (transpose+cast)
//                    bid<48  : vwb = bf16(vw)
//                    bid==48 : scalar coefficients
//                    bid>48  : zero the CSR 'start' array (replaces memset)
// ---------------------------------------------------------------------------
__global__ __launch_bounds__(256) void k_prep(const float* __restrict__ W,
                                              const float* __restrict__ vw,
                                              const float* __restrict__ lg,
                                              const float* __restrict__ mg,
                                              short* __restrict__ Wt,
                                              short* __restrict__ vwb,
                                              float* __restrict__ sc,
                                              int* __restrict__ start, int M) {
    const int bid = blockIdx.x, tid = threadIdx.x;
    if (bid < 32) {
        __shared__ float T[32][33];
        int kt = bid >> 2, ct = bid & 3;
        int r = tid >> 3, c4 = (tid & 7) << 2;
        float4 v = *(const float4*)(W + (size_t)(kt*32 + r) * EDIM + ct*32 + c4);
        T[c4+0][r] = v.x; T[c4+1][r] = v.y; T[c4+2][r] = v.z; T[c4+3][r] = v.w;
        __syncthreads();
        int c = tid >> 3, k4 = (tid & 7) << 2;
        short4 s;
        s.x = f2b(T[c][k4+0]); s.y = f2b(T[c][k4+1]);
        s.z = f2b(T[c][k4+2]); s.w = f2b(T[c][k4+3]);
        *(short4*)(Wt + (size_t)(ct*32 + c) * FIN + kt*32 + k4) = s;
    } else if (bid < 48) {
        int idx = ((bid - 32) * 256 + tid) * 4;     // 16 blocks cover 128*128
        float4 v = *(const float4*)(vw + idx);
        short4 s;
        s.x = f2b(v.x); s.y = f2b(v.y); s.z = f2b(v.z); s.w = f2b(v.w);
        *(short4*)(vwb + idx) = s;
    } else if (bid == 48) {
        if (tid == 0) {
            const float a0 = -1e-9f, a1 = 1.0f + 1e-9f;
            float a_low = 0.f, b_low = 0.f, a_mid = 0.f, c_mid = 0.f;
            for (int i = 0; i < 5; ++i) {
                float l0 = fmaxf(lg[2*i], 0.f), l1 = fmaxf(lg[2*i+1], 0.f);
                a_low += l0 * a0 + l1 * a1;
                b_low += l0 * (1.f - a0) + l1 * (1.f - a1);
                float m0 = fmaxf(mg[2*i], 0.f), m1 = fmaxf(mg[2*i+1], 0.f);
                a_mid += m0 + m1;
                c_mid += m0 * a0 + m1 * a1;
            }
            sc[0] = a_low + a_mid;
            sc[1] = b_low - c_mid;
        }
    } else {
        int i = (bid - 49) * 256 + tid;
        if (i < M) start[i] = 0;
    }
}

// ---------------------------------------------------------------------------
// Fused MFMA GEMM: Y[M,128](bf16) = relu(F[M,256] @ W) @ vw^T
// 512 threads (8 waves), BM=128, wave owns 16 rows. Wt+vwb staged in LDS
// (XOR-swizzled); F loads issued upfront; zero extra syncthreads.
// ---------------------------------------------------------------------------
__global__ __launch_bounds__(512) void k_fused(const float* __restrict__ F,
                                               const short* __restrict__ Wt,
                                               const short* __restrict__ vwb,
                                               short* __restrict__ Yb, int M) {
    __shared__ short WtL[32768];     // 64KB, rows of 256 shorts (32 x 16B chunks)
    __shared__ short vwL[16384];     // 32KB, rows of 128 shorts (16 x 16B chunks)
    __shared__ short Sb[128 * 136];  // 34.8KB wave-private transpose slabs

    const int tid  = threadIdx.x;
    const int wave = tid >> 6, lane = tid & 63;
    const int l15  = lane & 15, lhi = lane >> 4;
    const int bm   = blockIdx.x * 128;
    const int wrow = wave * 16;
    const int swz  = l15 & 7;                      // row-derived XOR for frags

    // ---- issue ALL F loads for this lane's A-row (deep ILP) ----
    const int gr_a = bm + wrow + l15;
    const bool va  = gr_a < M;
    const float* fp = F + (size_t)(va ? gr_a : 0) * FIN + lhi * 8;
    float4 fa[16];
    #pragma unroll
    for (int t = 0; t < 16; ++t) {
        fa[t] = make_float4(0.f, 0.f, 0.f, 0.f);
        if (va) fa[t] = *(const float4*)(fp + (t >> 1) * 32 + (t & 1) * 4);
    }

    // ---- stage Wt: 4096 16B chunks, swizzled; coalesced global reads ----
    #pragma unroll
    for (int i = 0; i < 8; ++i) {
        int idx = tid + i * 512;                   // 0..4095
        int r = idx >> 5, c = idx & 31;
        int4 v = *(const int4*)(Wt + r * 256 + c * 8);
        *(int4*)(&WtL[r * 256 + ((c ^ (r & 7)) << 3)]) = v;
    }
    // ---- stage vwb: 2048 chunks ----
    #pragma unroll
    for (int i = 0; i < 4; ++i) {
        int idx = tid + i * 512;                   // 0..2047
        int r = idx >> 4, c = idx & 15;
        int4 v = *(const int4*)(vwb + r * 128 + c * 8);
        *(int4*)(&vwL[r * 128 + ((c ^ (r & 7)) << 3)]) = v;
    }
    __syncthreads();

    // ---- GEMM1: sup = relu(F @ W), K = 256 in 8 steps of 32, B from LDS ----
    f32x4 acc[8];
    #pragma unroll
    for (int b = 0; b < 8; ++b) acc[b] = (f32x4){0.f, 0.f, 0.f, 0.f};

    #pragma unroll
    for (int kt = 0; kt < 8; ++kt) {
        float4 a0 = fa[kt*2], a1 = fa[kt*2 + 1];
        bf16x8 af;
        af[0]=f2b(a0.x); af[1]=f2b(a0.y); af[2]=f2b(a0.z); af[3]=f2b(a0.w);
        af[4]=f2b(a1.x); af[5]=f2b(a1.y); af[6]=f2b(a1.z); af[7]=f2b(a1.w);
        #pragma unroll
        for (int nf = 0; nf < 8; ++nf) {
            bf16x8 bf = *(const bf16x8*)(&WtL[(nf*16 + l15) * 256 +
                                              (((kt*4 + lhi) ^ swz) << 3)]);
            acc[nf] = __builtin_amdgcn_mfma_f32_16x16x32_bf16(af, bf, acc[nf], 0, 0, 0);
        }
    }

    // ---- relu + bf16 -> wave-private slab (transpose D->A layout) ----
    #pragma unroll
    for (int nf = 0; nf < 8; ++nf)
        #pragma unroll
        for (int i = 0; i < 4; ++i)
            Sb[(wrow + lhi*4 + i) * 136 + nf*16 + l15] = f2b(fmaxf(acc[nf][i], 0.f));

    // ---- GEMM2: Y = sup @ vw^T, K = 128 in 4 steps, all LDS ----
    f32x4 acc2[8];
    #pragma unroll
    for (int b = 0; b < 8; ++b) acc2[b] = (f32x4){0.f, 0.f, 0.f, 0.f};

    #pragma unroll
    for (int ks = 0; ks < 4; ++ks) {
        bf16x8 af2 = *(const bf16x8*)(&Sb[(wrow + l15) * 136 + ks*32 + lhi*8]);
        #pragma unroll
        for (int nf = 0; nf < 8; ++nf) {
            bf16x8 bf2 = *(const bf16x8*)(&vwL[(nf*16 + l15) * 128 +
                                               (((ks*4 + lhi) ^ swz) << 3)]);
            acc2[nf] = __builtin_amdgcn_mfma_f32_16x16x32_bf16(af2, bf2, acc2[nf], 0, 0, 0);
        }
    }

    // ---- Y -> slab (same wave-private rows), then coalesced store ----
    #pragma unroll
    for (int nf = 0; nf < 8; ++nf)
        #pragma unroll
        for (int i = 0; i < 4; ++i)
            Sb[(wrow + lhi*4 + i) * 136 + nf*16 + l15] = f2b(acc2[nf][i]);

    const int srow = lane >> 2;                    // 16 rows, 4 lanes each
    const int sch  = (lane & 3) * 32;              // 64B chunk of the row
    const int gr_s = bm + wrow + srow;
    if (gr_s < M) {
        #pragma unroll
        for (int r = 0; r < 4; ++r) {
            float4 t = *(const float4*)(&Sb[(wrow + srow) * 136 + sch + r*8]);
            *(float4*)(Yb + (size_t)gr_s * EDIM + sch + r*8) = t;
        }
    }
}

// ---------------------------------------------------------------------------
// CSR build, XCD-partitioned: rows are split into 8 contiguous partitions;
// block (bid & 7) handles only rows of its partition (XCD round-robin
// heuristic -> each colw/start region is written by ONE XCD's L2, killing
// the 8x cross-XCD write amplification). Each partition scans all edges
// with coalesced loads; non-matching lanes are predicated off.
// ---------------------------------------------------------------------------
__global__ void k_count(const int* __restrict__ ei, int* __restrict__ start,
                        int ne, int R) {
    int part = blockIdx.x & 7;
    int e = (blockIdx.x >> 3) * 256 + threadIdx.x;
    if (e >= ne) return;
    int r = ei[e];
    int lo = part * R;
    if (r >= lo && r < lo + R) atomicAdd(&start[r], 1);
}

__global__ void k_fill(const int* __restrict__ ei, const float* __restrict__ ew,
                       int* __restrict__ start, int2* __restrict__ colw,
                       int ne, int R) {
    int part = blockIdx.x & 7;
    int e = (blockIdx.x >> 3) * 256 + threadIdx.x;
    if (e >= ne) return;
    int r   = ei[e];
    int col = ei[ne + e];          // coalesced (all lanes)
    float w = ew[e];               // coalesced (all lanes)
    int lo = part * R;
    if (r >= lo && r < lo + R) {
        int pos = atomicAdd(&start[r], 1);   // start[r] ends as end-of-row r
        colw[pos] = make_int2(col, __float_as_int(w));
    }
}

// ---------------------------------------------------------------------------
// Scan (3 small kernels): exclusive prefix sum over per-row counts
// ---------------------------------------------------------------------------
__global__ void k_scan1(const int* __restrict__ cnt, int* __restrict__ bsum, int n) {
    __shared__ int sh[256];
    int t = threadIdx.x;
    int i = blockIdx.x * 256 + t;
    sh[t] = (i < n) ? cnt[i] : 0;
    __syncthreads();
    for (int s = 128; s > 0; s >>= 1) {
        if (t < s) sh[t] += sh[t + s];
        __syncthreads();
    }
    if (t == 0) bsum[blockIdx.x] = sh[0];
}

__global__ void k_scan2(int* __restrict__ bsum, int nb) {
    __shared__ int sh[256];
    int t = threadIdx.x;
    int v = (t < nb) ? bsum[t] : 0;
    sh[t] = v;
    __syncthreads();
    for (int off = 1; off < 256; off <<= 1) {
        int x = (t >= off) ? sh[t - off] : 0;
        __syncthreads();
        sh[t] += x;
        __syncthreads();
    }
    if (t < nb) bsum[t] = sh[t] - v;   // exclusive
}

__global__ void k_scan3(int* __restrict__ start, const int* __restrict__ bsum, int n) {
    __shared__ int sh[256];
    int t = threadIdx.x;
    int i = blockIdx.x * 256 + t;
    int v = (i < n) ? start[i] : 0;
    sh[t] = v;
    __syncthreads();
    for (int off = 1; off < 256; off <<= 1) {
        int x = (t >= off) ? sh[t - off] : 0;
        __syncthreads();
        sh[t] += x;
        __syncthreads();
    }
    if (i < n) start[i] = sh[t] - v + bsum[blockIdx.x];   // exclusive start
}

// ---------------------------------------------------------------------------
// Fused gather + epilogue: out[row] = Aa * sum_e w_e * Y[col_e] + Bb*Y[row] + 2*vb
// One wave per row; wave-uniform colw loads, 4-way unrolled.
// ---------------------------------------------------------------------------
__global__ __launch_bounds__(256) void k_gather(const int2* __restrict__ colw,
                                                const int* __restrict__ start,
                                                const __hip_bfloat162* __restrict__ Yb,
                                                const float* __restrict__ vb,
                                                const float* __restrict__ sc,
                                                float* __restrict__ out, int n) {
    int wave = (blockIdx.x * blockDim.x + threadIdx.x) >> 6;
    int lane = threadIdx.x & 63;
    if (wave >= n) return;
    int begin = __builtin_amdgcn_readfirstlane((wave == 0) ? 0 : start[wave - 1]);
    int end   = __builtin_amdgcn_readfirstlane(start[wave]);
    const float Aa = sc[0];
    const float Bb = sc[1];

    float2 acc = make_float2(0.f, 0.f);
    int j = begin;
    for (; j + 4 <= end; j += 4) {
        int2 e0 = colw[j+0], e1 = colw[j+1], e2 = colw[j+2], e3 = colw[j+3];
        float2 v0 = __bfloat1622float2(Yb[(size_t)e0.x * 64 + lane]);
        float2 v1 = __bfloat1622float2(Yb[(size_t)e1.x * 64 + lane]);
        float2 v2 = __bfloat1622float2(Yb[(size_t)e2.x * 64 + lane]);
        float2 v3 = __bfloat1622float2(Yb[(size_t)e3.x * 64 + lane]);
        float w0 = __int_as_float(e0.y), w1 = __int_as_float(e1.y);
        float w2 = __int_as_float(e2.y), w3 = __int_as_float(e3.y);
        acc.x = fmaf(w0, v0.x, acc.x); acc.y = fmaf(w0, v0.y, acc.y);
        acc.x = fmaf(w1, v1.x, acc.x); acc.y = fmaf(w1, v1.y, acc.y);
        acc.x = fmaf(w2, v2.x, acc.x); acc.y = fmaf(w2, v2.y, acc.y);
        acc.x = fmaf(w3, v3.x, acc.x); acc.y = fmaf(w3, v3.y, acc.y);
    }
    for (; j < end; ++j) {
        int2 e = colw[j];
        float w = __int_as_float(e.y);
        float2 v = __bfloat1622float2(Yb[(size_t)e.x * 64 + lane]);
        acc.x = fmaf(w, v.x, acc.x);
        acc.y = fmaf(w, v.y, acc.y);
    }
    float2 y = __bfloat1622float2(Yb[(size_t)wave * 64 + lane]);
    float2 b = *(const float2*)(vb + lane * 2);
    float2 o;
    o.x = fmaf(Aa, acc.x, fmaf(Bb, y.x, 2.f * b.x));
    o.y = fmaf(Aa, acc.y, fmaf(Bb, y.y, 2.f * b.y));
    *(float2*)(out + (size_t)wave * EDIM + lane * 2) = o;
}

// ---------------------------------------------------------------------------
extern "C" void kernel_launch(void* const* d_in, const int* in_sizes, int n_in,
                              void* d_out, int out_size, void* d_ws, size_t ws_size,
                              hipStream_t stream) {
    const float* feature = (const float*)d_in[0];
    const int*   eidx    = (const int*)d_in[1];   // [2, NE] int32
    const float* ew      = (const float*)d_in[2];
    const float* weight  = (const float*)d_in[3];
    const float* lg      = (const float*)d_in[4];
    const float* mg      = (const float*)d_in[5];
    // d_in[6..9] = q_w,q_b,k_w,k_b provably unused: softmax over the query axis
    // followed by sum over the query axis makes each k-column of w sum to 1.
    const float* vw      = (const float*)d_in[10];
    const float* vb      = (const float*)d_in[11];
    float* out = (float*)d_out;

    const int M  = in_sizes[0] / FIN;   // 50000
    const int NE = in_sizes[2];         // 600000

    // workspace layout (~18 MB)
    char* ws = (char*)d_ws;
    short* Yb   = (short*)ws;                                   // M*128*2 = 12.8 MB
    char* p = ws + (size_t)M * EDIM * 2;
    int2*  colw = (int2*)p;          p += (size_t)NE * 8;       // 4.8 MB
    int*   start = (int*)p;          p += (size_t)M * 4;        // 200 KB
    int*   bsum = (int*)p;           p += 256 * 4;
    short* Wt   = (short*)p;         p += (size_t)EDIM * FIN * 2;  // 64 KB
    short* vwb  = (short*)p;         p += (size_t)EDIM * EDIM * 2; // 32 KB
    float* sc   = (float*)p;

    const int nb = (M + 255) / 256;           // 196 scan blocks (<=256)
    const int R  = (M + 7) / 8;               // rows per XCD partition

    k_prep<<<49 + nb, 256, 0, stream>>>(weight, vw, lg, mg, Wt, vwb, sc, start, M);

    int gFused = (M + 127) / 128;
    k_fused<<<gFused, 512, 0, stream>>>(feature, Wt, vwb, Yb, M);

    int gE8 = ((NE + 255) / 256) * 8;         // 8 XCD partitions x edge chunks
    k_count<<<gE8, 256, 0, stream>>>(eidx, start, NE, R);
    k_scan1<<<nb, 256, 0, stream>>>(start, bsum, M);
    k_scan2<<<1, 256, 0, stream>>>(bsum, nb);
    k_scan3<<<nb, 256, 0, stream>>>(start, bsum, M);
    k_fill<<<gE8, 256, 0, stream>>>(eidx, ew, start, colw, NE, R);

    int gGather = ((M * 64) + 255) / 256;     // one wave per row
    k_gather<<<gGather, 256, 0, stream>>>(colw, start, (const __hip_bfloat162*)Yb,
                                          vb, sc, out, M);
}

// Round 8
// 118.442 us; speedup vs baseline: 5.0788x; 1.0720x over previous
//
#include <hip/hip_runtime.h>
#include <hip/hip_bf16.h>

static constexpr int EDIM = 128;   // embedding size
static constexpr int FIN  = 256;   // input features

typedef __attribute__((ext_vector_type(8))) short bf16x8;
typedef __attribute__((ext_vector_type(4))) float f32x4;

__device__ inline short f2b(float f) {
    __hip_bfloat16 h = __float2bfloat16(f);
    return *reinterpret_cast<short*>(&h);
}

// ---------------------------------------------------------------------------
// Prep: build FRAGMENT-MAJOR bf16 weights so every MFMA B-fragment load in
// k_mega is one coalesced 1KB wave read (no LDS staging, L1-resident).
//   WtF[((kt*8+nf)*64+lane)*8 + i] = bf16(W[kt*32 + (lane>>4)*8 + i][nf*16 + (lane&15)])
//   vwF[((ks*8+nf)*64+lane)*8 + i] = bf16(vw[nf*16 + (lane&15)][ks*32 + (lane>>4)*8 + i])
// plus scalar coefficients and zeroing the CSR 'start' array.
// ---------------------------------------------------------------------------
__global__ __launch_bounds__(256) void k_prep(const float* __restrict__ W,
                                              const float* __restrict__ vw,
                                              const float* __restrict__ lg,
                                              const float* __restrict__ mg,
                                              short* __restrict__ WtF,
                                              short* __restrict__ vwF,
                                              float* __restrict__ sc,
                                              int* __restrict__ start, int M) {
    const int bid = blockIdx.x, tid = threadIdx.x;
    if (bid < 16) {                                // WtF: 4096 fragments
        int idx = bid * 256 + tid;                 // (kt,nf,lane)
        int kt = idx >> 9, rem = idx & 511;
        int nf = rem >> 6, lane = rem & 63;
        int l15 = lane & 15, lhi = lane >> 4;
        bf16x8 fr;
        #pragma unroll
        for (int i = 0; i < 8; ++i)
            fr[i] = f2b(W[(size_t)(kt*32 + lhi*8 + i) * EDIM + nf*16 + l15]);
        *(bf16x8*)(WtF + (size_t)idx * 8) = fr;
    } else if (bid < 24) {                         // vwF: 2048 fragments
        int idx = (bid - 16) * 256 + tid;          // (ks,nf,lane)
        int ks = idx >> 9, rem = idx & 511;
        int nf = rem >> 6, lane = rem & 63;
        int l15 = lane & 15, lhi = lane >> 4;
        bf16x8 fr;
        #pragma unroll
        for (int i = 0; i < 8; ++i)
            fr[i] = f2b(vw[(size_t)(nf*16 + l15) * EDIM + ks*32 + lhi*8 + i]);
        *(bf16x8*)(vwF + (size_t)idx * 8) = fr;
    } else if (bid == 24) {
        if (tid == 0) {
            const float a0 = -1e-9f, a1 = 1.0f + 1e-9f;
            float a_low = 0.f, b_low = 0.f, a_mid = 0.f, c_mid = 0.f;
            for (int i = 0; i < 5; ++i) {
                float l0 = fmaxf(lg[2*i], 0.f), l1 = fmaxf(lg[2*i+1], 0.f);
                a_low += l0 * a0 + l1 * a1;
                b_low += l0 * (1.f - a0) + l1 * (1.f - a1);
                float m0 = fmaxf(mg[2*i], 0.f), m1 = fmaxf(mg[2*i+1], 0.f);
                a_mid += m0 + m1;
                c_mid += m0 * a0 + m1 * a1;
            }
            sc[0] = a_low + a_mid;
            sc[1] = b_low - c_mid;
        }
    } else {
        int i = (bid - 25) * 256 + tid;
        if (i < M) start[i] = 0;
    }
}

// ---------------------------------------------------------------------------
// Mega kernel:
//  blocks [0, gFused)        : fused MFMA GEMM  Y = relu(F@W) @ vw^T
//                              BM=64, 4 waves, wave-private Sb, NO barriers.
//  blocks [gFused, +gE8)     : XCD-partitioned edge count (independent work,
//                              overlaps the latency-bound GEMM blocks).
// ---------------------------------------------------------------------------
__global__ __launch_bounds__(256) void k_mega(const float* __restrict__ F,
                                              const short* __restrict__ WtF,
                                              const short* __restrict__ vwF,
                                              short* __restrict__ Yb,
                                              const int* __restrict__ ei,
                                              int* __restrict__ start,
                                              int M, int ne, int R) {
    __shared__ short Sb[64 * 136];   // 17.4KB wave-private transpose slabs
    const int gFused = (M + 63) >> 6;
    const int bid = blockIdx.x, tid = threadIdx.x;

    if (bid >= gFused) {             // ---- count path ----
        int bid2 = bid - gFused;
        int part = bid2 & 7;
        int e = (bid2 >> 3) * 256 + tid;
        if (e >= ne) return;
        int r = ei[e];
        int lo = part * R;
        if (r >= lo && r < lo + R) atomicAdd(&start[r], 1);
        return;
    }

    // ---- fused GEMM path ----
    const int wave = tid >> 6, lane = tid & 63;
    const int l15  = lane & 15, lhi = lane >> 4;
    const int bm   = bid * 64;
    const int wrow = wave * 16;

    // issue ALL F loads for this lane's A-row upfront (deep ILP)
    const int gr_a = bm + wrow + l15;
    const bool va  = gr_a < M;
    const float* fp = F + (size_t)(va ? gr_a : 0) * FIN + lhi * 8;
    float4 fa[16];
    #pragma unroll
    for (int t = 0; t < 16; ++t) {
        fa[t] = make_float4(0.f, 0.f, 0.f, 0.f);
        if (va) fa[t] = *(const float4*)(fp + (t >> 1) * 32 + (t & 1) * 4);
    }

    // GEMM1: sup = relu(F @ W); B-frags are coalesced broadcast reads
    f32x4 acc[8];
    #pragma unroll
    for (int b = 0; b < 8; ++b) acc[b] = (f32x4){0.f, 0.f, 0.f, 0.f};

    #pragma unroll
    for (int kt = 0; kt < 8; ++kt) {
        float4 a0 = fa[kt*2], a1 = fa[kt*2 + 1];
        bf16x8 af;
        af[0]=f2b(a0.x); af[1]=f2b(a0.y); af[2]=f2b(a0.z); af[3]=f2b(a0.w);
        af[4]=f2b(a1.x); af[5]=f2b(a1.y); af[6]=f2b(a1.z); af[7]=f2b(a1.w);
        #pragma unroll
        for (int nf = 0; nf < 8; ++nf) {
            bf16x8 bf = *(const bf16x8*)(WtF + (size_t)((kt*8 + nf)*64 + lane) * 8);
            acc[nf] = __builtin_amdgcn_mfma_f32_16x16x32_bf16(af, bf, acc[nf], 0, 0, 0);
        }
    }

    // relu + bf16 -> wave-private slab (D layout -> A layout transpose)
    #pragma unroll
    for (int nf = 0; nf < 8; ++nf)
        #pragma unroll
        for (int i = 0; i < 4; ++i)
            Sb[(wrow + lhi*4 + i) * 136 + nf*16 + l15] = f2b(fmaxf(acc[nf][i], 0.f));

    // GEMM2: Y = sup @ vw^T
    f32x4 acc2[8];
    #pragma unroll
    for (int b = 0; b < 8; ++b) acc2[b] = (f32x4){0.f, 0.f, 0.f, 0.f};

    #pragma unroll
    for (int ks = 0; ks < 4; ++ks) {
        bf16x8 af2 = *(const bf16x8*)(&Sb[(wrow + l15) * 136 + ks*32 + lhi*8]);
        #pragma unroll
        for (int nf = 0; nf < 8; ++nf) {
            bf16x8 bf2 = *(const bf16x8*)(vwF + (size_t)((ks*8 + nf)*64 + lane) * 8);
            acc2[nf] = __builtin_amdgcn_mfma_f32_16x16x32_bf16(af2, bf2, acc2[nf], 0, 0, 0);
        }
    }

    // Y -> slab, then coalesced bf16 store
    #pragma unroll
    for (int nf = 0; nf < 8; ++nf)
        #pragma unroll
        for (int i = 0; i < 4; ++i)
            Sb[(wrow + lhi*4 + i) * 136 + nf*16 + l15] = f2b(acc2[nf][i]);

    const int srow = lane >> 2;                    // 16 rows, 4 lanes each
    const int sch  = (lane & 3) * 32;              // 64B chunk of the row
    const int gr_s = bm + wrow + srow;
    if (gr_s < M) {
        #pragma unroll
        for (int r = 0; r < 4; ++r) {
            float4 t = *(const float4*)(&Sb[(wrow + srow) * 136 + sch + r*8]);
            *(float4*)(Yb + (size_t)gr_s * EDIM + sch + r*8) = t;
        }
    }
}

// ---------------------------------------------------------------------------
// Scan (3 small kernels): exclusive prefix sum over per-row counts
// ---------------------------------------------------------------------------
__global__ void k_scan1(const int* __restrict__ cnt, int* __restrict__ bsum, int n) {
    __shared__ int sh[256];
    int t = threadIdx.x;
    int i = blockIdx.x * 256 + t;
    sh[t] = (i < n) ? cnt[i] : 0;
    __syncthreads();
    for (int s = 128; s > 0; s >>= 1) {
        if (t < s) sh[t] += sh[t + s];
        __syncthreads();
    }
    if (t == 0) bsum[blockIdx.x] = sh[0];
}

__global__ void k_scan2(int* __restrict__ bsum, int nb) {
    __shared__ int sh[256];
    int t = threadIdx.x;
    int v = (t < nb) ? bsum[t] : 0;
    sh[t] = v;
    __syncthreads();
    for (int off = 1; off < 256; off <<= 1) {
        int x = (t >= off) ? sh[t - off] : 0;
        __syncthreads();
        sh[t] += x;
        __syncthreads();
    }
    if (t < nb) bsum[t] = sh[t] - v;   // exclusive
}

__global__ void k_scan3(int* __restrict__ start, const int* __restrict__ bsum, int n) {
    __shared__ int sh[256];
    int t = threadIdx.x;
    int i = blockIdx.x * 256 + t;
    int v = (i < n) ? start[i] : 0;
    sh[t] = v;
    __syncthreads();
    for (int off = 1; off < 256; off <<= 1) {
        int x = (t >= off) ? sh[t - off] : 0;
        __syncthreads();
        sh[t] += x;
        __syncthreads();
    }
    if (i < n) start[i] = sh[t] - v + bsum[blockIdx.x];   // exclusive start
}

// ---------------------------------------------------------------------------
// Fill, XCD-partitioned: block (bid&7) handles only rows in its partition so
// each colw/start region is written by one XCD's L2 (no cross-XCD ping-pong).
// ---------------------------------------------------------------------------
__global__ void k_fill(const int* __restrict__ ei, const float* __restrict__ ew,
                       int* __restrict__ start, int2* __restrict__ colw,
                       int ne, int R) {
    int part = blockIdx.x & 7;
    int e = (blockIdx.x >> 3) * 256 + threadIdx.x;
    if (e >= ne) return;
    int r   = ei[e];
    int col = ei[ne + e];
    float w = ew[e];
    int lo = part * R;
    if (r >= lo && r < lo + R) {
        int pos = atomicAdd(&start[r], 1);   // start[r] ends as end-of-row r
        colw[pos] = make_int2(col, __float_as_int(w));
    }
}

// ---------------------------------------------------------------------------
// Fused gather + epilogue: out[row] = Aa * sum_e w_e * Y[col_e] + Bb*Y[row] + 2*vb
// One wave per row; wave-uniform colw loads, 8-way unrolled for MLP.
// ---------------------------------------------------------------------------
__global__ __launch_bounds__(256) void k_gather(const int2* __restrict__ colw,
                                                const int* __restrict__ start,
                                                const __hip_bfloat162* __restrict__ Yb,
                                                const float* __restrict__ vb,
                                                const float* __restrict__ sc,
                                                float* __restrict__ out, int n) {
    int wave = (blockIdx.x * blockDim.x + threadIdx.x) >> 6;
    int lane = threadIdx.x & 63;
    if (wave >= n) return;
    int begin = __builtin_amdgcn_readfirstlane((wave == 0) ? 0 : start[wave - 1]);
    int end   = __builtin_amdgcn_readfirstlane(start[wave]);
    const float Aa = sc[0];
    const float Bb = sc[1];

    float2 acc = make_float2(0.f, 0.f);
    int j = begin;
    for (; j + 8 <= end; j += 8) {
        float2 v[8]; float w[8];
        #pragma unroll
        for (int u = 0; u < 8; ++u) {
            int2 e = colw[j + u];
            w[u] = __int_as_float(e.y);
            v[u] = __bfloat1622float2(Yb[(size_t)e.x * 64 + lane]);
        }
        #pragma unroll
        for (int u = 0; u < 8; ++u) {
            acc.x = fmaf(w[u], v[u].x, acc.x);
            acc.y = fmaf(w[u], v[u].y, acc.y);
        }
    }
    for (; j + 4 <= end; j += 4) {
        float2 v[4]; float w[4];
        #pragma unroll
        for (int u = 0; u < 4; ++u) {
            int2 e = colw[j + u];
            w[u] = __int_as_float(e.y);
            v[u] = __bfloat1622float2(Yb[(size_t)e.x * 64 + lane]);
        }
        #pragma unroll
        for (int u = 0; u < 4; ++u) {
            acc.x = fmaf(w[u], v[u].x, acc.x);
            acc.y = fmaf(w[u], v[u].y, acc.y);
        }
    }
    for (; j < end; ++j) {
        int2 e = colw[j];
        float w = __int_as_float(e.y);
        float2 v = __bfloat1622float2(Yb[(size_t)e.x * 64 + lane]);
        acc.x = fmaf(w, v.x, acc.x);
        acc.y = fmaf(w, v.y, acc.y);
    }
    float2 y = __bfloat1622float2(Yb[(size_t)wave * 64 + lane]);
    float2 b = *(const float2*)(vb + lane * 2);
    float2 o;
    o.x = fmaf(Aa, acc.x, fmaf(Bb, y.x, 2.f * b.x));
    o.y = fmaf(Aa, acc.y, fmaf(Bb, y.y, 2.f * b.y));
    *(float2*)(out + (size_t)wave * EDIM + lane * 2) = o;
}

// ---------------------------------------------------------------------------
extern "C" void kernel_launch(void* const* d_in, const int* in_sizes, int n_in,
                              void* d_out, int out_size, void* d_ws, size_t ws_size,
                              hipStream_t stream) {
    const float* feature = (const float*)d_in[0];
    const int*   eidx    = (const int*)d_in[1];   // [2, NE] int32
    const float* ew      = (const float*)d_in[2];
    const float* weight  = (const float*)d_in[3];
    const float* lg      = (const float*)d_in[4];
    const float* mg      = (const float*)d_in[5];
    // d_in[6..9] = q_w,q_b,k_w,k_b provably unused: softmax over the query axis
    // followed by sum over the query axis makes each k-column of w sum to 1.
    const float* vw      = (const float*)d_in[10];
    const float* vb      = (const float*)d_in[11];
    float* out = (float*)d_out;

    const int M  = in_sizes[0] / FIN;   // 50000
    const int NE = in_sizes[2];         // 600000

    // workspace layout (~18 MB)
    char* ws = (char*)d_ws;
    short* Yb   = (short*)ws;                                   // M*128*2 = 12.8 MB
    char* p = ws + (size_t)M * EDIM * 2;
    int2*  colw = (int2*)p;          p += (size_t)NE * 8;       // 4.8 MB
    int*   start = (int*)p;          p += (size_t)M * 4;        // 200 KB
    int*   bsum = (int*)p;           p += 256 * 4;
    short* WtF  = (short*)p;         p += (size_t)EDIM * FIN * 2;  // 64 KB frag-major
    short* vwF  = (short*)p;         p += (size_t)EDIM * EDIM * 2; // 32 KB frag-major
    float* sc   = (float*)p;

    const int nb = (M + 255) / 256;           // 196 scan blocks (<=256)
    const int R  = (M + 7) / 8;               // rows per XCD partition

    k_prep<<<25 + nb, 256, 0, stream>>>(weight, vw, lg, mg, WtF, vwF, sc, start, M);

    const int gFused = (M + 63) / 64;
    const int gE8    = ((NE + 255) / 256) * 8;
    k_mega<<<gFused + gE8, 256, 0, stream>>>(feature, WtF, vwF, Yb,
                                             eidx, start, M, NE, R);

    k_scan1<<<nb, 256, 0, stream>>>(start, bsum, M);
    k_scan2<<<1, 256, 0, stream>>>(bsum, nb);
    k_scan3<<<nb, 256, 0, stream>>>(start, bsum, M);
    k_fill<<<gE8, 256, 0, stream>>>(eidx, ew, start, colw, NE, R);

    int gGather = ((M * 64) + 255) / 256;     // one wave per row
    k_gather<<<gGather, 256, 0, stream>>>(colw, start, (const __hip_bfloat162*)Yb,
                                          vb, sc, out, M);
}